// Round 15
// baseline (337.177 us; speedup 1.0000x reference)
//
#include <hip/hip_runtime.h>
#include <math.h>

#define N_NODES 20000
#define N_EDG   320000
#define NB      64
#define EMBD    32
#define HIDD    128
#define NHEAD   4
#define OUTC    512      // H * HID
#define LN_EPS  1e-5f
#define NEG_SLOPE 0.2f
#define PAD     64       // padded-CSR slots per node (max deg ~40 for this dataset)

typedef unsigned int u32;
typedef unsigned short u16;
typedef __attribute__((ext_vector_type(8))) short s16x8;
typedef __attribute__((ext_vector_type(4))) float f32x4;

__device__ __forceinline__ float lrelu(float x){ return x >= 0.f ? x : NEG_SLOPE * x; }

__device__ __forceinline__ float2 bf2f(u32 p){
  float2 r;
  r.x = __uint_as_float(p << 16);
  r.y = __uint_as_float(p & 0xffff0000u);
  return r;
}
__device__ __forceinline__ float bf1f(u16 v){ return __uint_as_float(((u32)v) << 16); }
__device__ __forceinline__ u16 f2bf(float a){
  u32 ua = __float_as_uint(a);
  return (u16)((ua + 0x7fffu + ((ua >> 16) & 1u)) >> 16);
}
__device__ __forceinline__ u32 pack2bf(float a, float b){
  return (u32)f2bf(a) | ((u32)f2bf(b) << 16);
}

// ---------------- fused setup: fold + cvt_w + cvt_x + bounds + edgescatter ----------------
// blocks [0,15): fold; [15,591): cvt_w; [591,3091): cvt_x; [3091,3170): bounds;
// [3170,4420): edge scatter+projection (self-sufficient: recomputes v_e locally)
__global__ __launch_bounds__(256) void k_setup(const float* __restrict__ W0,
                                               const float* __restrict__ W1,
                                               const float* __restrict__ W2,
                                               const float* __restrict__ lin_edge,
                                               const float* __restrict__ att_src,
                                               const float* __restrict__ att_dst,
                                               const float* __restrict__ att_edge,
                                               const float* __restrict__ x,
                                               const int* __restrict__ batch,
                                               const float* __restrict__ ea,
                                               const int* __restrict__ src,
                                               const int* __restrict__ dst,
                                               int* __restrict__ cursor,
                                               float* __restrict__ vfold,
                                               u16* __restrict__ wt0, u16* __restrict__ wt1,
                                               u16* __restrict__ wt2, u16* __restrict__ xb,
                                               int* __restrict__ bnd,
                                               u32* __restrict__ erec){
  int b = blockIdx.x;
  if (b < 15){
    int L = b / 5;
    int in_dim = L ? HIDD : EMBD;
    const float* W  = (L == 0) ? W0 : ((L == 1) ? W1 : W2);
    const float* We = lin_edge + (size_t)L * EMBD * OUTC;
    const float* as = att_src + L * 512;
    const float* ad = att_dst + L * 512;
    const float* ae = att_edge + L * 512;
    float* vf = vfold + L * 1152;
    int j = (b % 5) * 256 + threadIdx.x;
    int nsrc = in_dim * NHEAD;
    if (j < nsrc){
      int k = j >> 2, h = j & 3;
      float s = 0.f;
      for (int c = 0; c < HIDD; ++c) s += W[k * OUTC + h * HIDD + c] * as[h * HIDD + c];
      vf[k * 4 + h] = s;
    } else if (j < 2 * nsrc){
      int jj = j - nsrc; int k = jj >> 2, h = jj & 3;
      float s = 0.f;
      for (int c = 0; c < HIDD; ++c) s += W[k * OUTC + h * HIDD + c] * ad[h * HIDD + c];
      vf[512 + k * 4 + h] = s;
    } else if (j < 2 * nsrc + EMBD * NHEAD){
      int jj = j - 2 * nsrc; int k = jj >> 2, h = jj & 3;
      float s = 0.f;
      for (int c = 0; c < HIDD; ++c) s += We[k * OUTC + h * HIDD + c] * ae[h * HIDD + c];
      vf[1024 + k * 4 + h] = s;
    }
  } else if (b < 591){
    int idx = (b - 15) * 256 + threadIdx.x;
    if (idx < 16384){
      int n = idx >> 5, k = idx & 31;
      wt0[idx] = f2bf(W0[(size_t)k * OUTC + n]);
    } else if (idx < 81920){
      int j = idx - 16384; int n = j >> 7, k = j & 127;
      wt1[j] = f2bf(W1[(size_t)k * OUTC + n]);
    } else {
      int j = idx - 81920; int n = j >> 7, k = j & 127;
      wt2[j] = f2bf(W2[(size_t)k * OUTC + n]);
    }
  } else if (b < 3091){
    int i = (b - 591) * 256 + threadIdx.x;
    if (i < N_NODES * EMBD) xb[i] = f2bf(x[i]);
  } else if (b < 3170){
    int n = (b - 3091) * 256 + threadIdx.x;
    if (n >= N_NODES) return;
    int bb = batch[n];
    int bp = (n == 0) ? -1 : batch[n - 1];
    for (int g = bp + 1; g <= bb; ++g) bnd[g] = n;
    if (n == N_NODES - 1){
      for (int g = bb + 1; g <= NB; ++g) bnd[g] = N_NODES;
    }
  } else {
    // ---- edge scatter + projection; v_e computed locally (no dependence on fold) ----
    __shared__ float vs[384];   // [L][k*4+h]
    int t = threadIdx.x;
    for (int j = t; j < 384; j += 256){
      int L = j >> 7, idx = j & 127;
      int k = idx >> 2, h = idx & 3;
      const float* We = lin_edge + (size_t)L * EMBD * OUTC;
      const float* ae = att_edge + L * 512 + h * HIDD;
      const float* wr = We + k * OUTC + h * HIDD;
      float s = 0.f;
      #pragma unroll 8
      for (int c = 0; c < HIDD; ++c) s = fmaf(wr[c], ae[c], s);
      vs[j] = s;
    }
    __syncthreads();
    int e = (b - 3170) * 256 + t;
    if (e >= N_EDG) return;
    int d = dst[e];
    int p = atomicAdd(&cursor[d], 1);
    if (p >= PAD) return;   // statistically impossible for this dataset
    float4 a[8];
    const float4* er = (const float4*)(ea + (size_t)e * EMBD);
    #pragma unroll
    for (int i = 0; i < 8; ++i) a[i] = er[i];
    u32 packed[6];
    #pragma unroll
    for (int L = 0; L < 3; ++L){
      const float* v = vs + L * 128;
      float ev[4] = {0,0,0,0};
      #pragma unroll
      for (int q = 0; q < 8; ++q){
        #pragma unroll
        for (int h = 0; h < 4; ++h){
          ev[h] += a[q].x * v[(q*4+0)*4+h] + a[q].y * v[(q*4+1)*4+h]
                 + a[q].z * v[(q*4+2)*4+h] + a[q].w * v[(q*4+3)*4+h];
        }
      }
      packed[L*2+0] = pack2bf(ev[0], ev[1]);
      packed[L*2+1] = pack2bf(ev[2], ev[3]);
    }
    u32* rp = erec + ((size_t)d * PAD + p) * 8;
    *(uint4*)rp       = make_uint4(packed[0], packed[1], packed[2], packed[3]);
    *(uint4*)(rp + 4) = make_uint4(packed[4], packed[5], (u32)src[e], 0u);
  }
}

__device__ __forceinline__ float wsum(float v){
  #pragma unroll
  for (int off = 32; off > 0; off >>= 1) v += __shfl_xor(v, off);
  return v;
}
__device__ __forceinline__ float wmax(float v){
  #pragma unroll
  for (int off = 32; off > 0; off >>= 1) v = fmaxf(v, __shfl_xor(v, off));
  return v;
}

// ---------------- MFMA bf16 GEMM + fused per-node s_src/s_dst (reads LDS tile) ----------------
template<int K>
__global__ __launch_bounds__(256) void k_gemm(const u16* __restrict__ Xb,
                                              const u16* __restrict__ Wt,
                                              u16* __restrict__ Hb,
                                              int M,
                                              const float* __restrict__ vf,
                                              float4* __restrict__ s_src,
                                              float4* __restrict__ s_dst){
  const int CH = K + 8;
  __shared__ u16 ldsA[64 * CH];
  __shared__ u16 ldsB[128 * CH];
  int bm = blockIdx.y * 64, bn = blockIdx.x * 128;
  int t = threadIdx.x;
  for (int f = t; f < 64 * (K / 8); f += 256){
    int row = f / (K / 8), c8 = f % (K / 8);
    int gm = bm + row;
    uint4 v = make_uint4(0, 0, 0, 0);
    if (gm < M) v = *(const uint4*)(Xb + (size_t)gm * K + c8 * 8);
    *(uint4*)&ldsA[row * CH + c8 * 8] = v;
  }
  for (int f = t; f < 128 * (K / 8); f += 256){
    int row = f / (K / 8), c8 = f % (K / 8);
    *(uint4*)&ldsB[row * CH + c8 * 8] = *(const uint4*)(Wt + (size_t)(bn + row) * K + c8 * 8);
  }
  __syncthreads();

  int w = t >> 6, lane = t & 63;
  int r = lane & 15, g = lane >> 4;
  f32x4 acc[8];
  #pragma unroll
  for (int i = 0; i < 8; ++i) acc[i] = (f32x4){0.f, 0.f, 0.f, 0.f};
  const u16* pa = &ldsA[(w * 16 + r) * CH + g * 8];
  #pragma unroll
  for (int k0 = 0; k0 < K; k0 += 32){
    s16x8 a = *(const s16x8*)(pa + k0);
    #pragma unroll
    for (int nf = 0; nf < 8; ++nf){
      s16x8 b = *(const s16x8*)(&ldsB[(nf * 16 + r) * CH + k0 + g * 8]);
      acc[nf] = __builtin_amdgcn_mfma_f32_16x16x32_bf16(a, b, acc[nf], 0, 0, 0);
    }
  }
  #pragma unroll
  for (int nf = 0; nf < 8; ++nf){
    #pragma unroll
    for (int i = 0; i < 4; ++i){
      int gm = bm + w * 16 + g * 4 + i;
      if (gm < M) Hb[(size_t)gm * OUTC + bn + nf * 16 + r] = f2bf(acc[nf][i]);
    }
  }

  // fused nodelin: column-0 blocks compute s_src/s_dst for their 64 rows, from LDS tile
  if (blockIdx.x == 0 && t < 64){
    int nn = bm + t;
    if (nn < M){
      float a[4] = {0,0,0,0}, d[4] = {0,0,0,0};
      const u16* xr = &ldsA[t * CH];
      #pragma unroll 8
      for (int k = 0; k < K; ++k){
        float xv = bf1f(xr[k]);
        #pragma unroll
        for (int h = 0; h < 4; ++h){
          a[h] = fmaf(xv, vf[k*4+h], a[h]);
          d[h] = fmaf(xv, vf[512+k*4+h], d[h]);
        }
      }
      s_src[nn] = make_float4(a[0], a[1], a[2], a[3]);
      s_dst[nn] = make_float4(d[0], d[1], d[2], d[3]);
    }
  }
}

// ---------------- wave-per-node aggregation: padded CSR, single-tile fast path ----------------
__global__ __launch_bounds__(256) void k_aggr(const uint4* __restrict__ Hb4,
                                              const u32* __restrict__ erec,
                                              const float4* __restrict__ s_src4,
                                              const float4* __restrict__ s_dst4,
                                              const int* __restrict__ cursor,
                                              int L,
                                              const float* __restrict__ bias,
                                              const float* __restrict__ lng,
                                              const float* __restrict__ lnb,
                                              u16* __restrict__ XoutBf){
  __shared__ float4 wlds4[4][64];
  __shared__ int    slds[4][64];
  int wid  = threadIdx.x >> 6;
  int lane = threadIdx.x & 63;
  int n = blockIdx.x * 4 + wid;
  if (n >= N_NODES) return;
  int h = lane >> 4;
  int degn = cursor[n];
  int cnt = min(degn, PAD);

  float4 dd = s_dst4[n];
  float4 sn = s_src4[n];
  uint4 hv = Hb4[(size_t)n * 64 + lane];    // own row (prefetch)

  // ---- logits in registers, per-head max + ev-sum (lane-parallel) ----
  float4 v = make_float4(-1e30f, -1e30f, -1e30f, -1e30f);
  float4 evv = make_float4(0.f, 0.f, 0.f, 0.f);
  int sj = 0;
  if (lane < cnt){
    const u32* rp = erec + ((size_t)n * PAD + lane) * 8;
    uint2 ep = *(const uint2*)(rp + 2 * L);
    sj = (int)rp[6];
    float2 e01 = bf2f(ep.x), e23 = bf2f(ep.y);
    evv = make_float4(e01.x, e01.y, e23.x, e23.y);
    float4 ss = s_src4[sj];
    v.x = lrelu(ss.x + dd.x + evv.x);
    v.y = lrelu(ss.y + dd.y + evv.y);
    v.z = lrelu(ss.z + dd.z + evv.z);
    v.w = lrelu(ss.w + dd.w + evv.w);
  }
  float m0 = wmax(v.x), m1 = wmax(v.y), m2 = wmax(v.z), m3 = wmax(v.w);
  float pv0 = wsum(evv.x), pv1 = wsum(evv.y), pv2 = wsum(evv.z), pv3 = wsum(evv.w);
  float invd = 1.f / fmaxf((float)degn, 1.f);
  float ll0 = lrelu(sn.x + dd.x + pv0 * invd);
  float ll1 = lrelu(sn.y + dd.y + pv1 * invd);
  float ll2 = lrelu(sn.z + dd.z + pv2 * invd);
  float ll3 = lrelu(sn.w + dd.w + pv3 * invd);
  m0 = fmaxf(m0, ll0); m1 = fmaxf(m1, ll1);
  m2 = fmaxf(m2, ll2); m3 = fmaxf(m3, ll3);
  float mh  = (h == 0) ? m0 : ((h == 1) ? m1 : ((h == 2) ? m2 : m3));
  float llh = (h == 0) ? ll0 : ((h == 1) ? ll1 : ((h == 2) ? ll2 : ll3));

  float s = __expf(llh - mh);
  float acc[8];
  { float2 p0 = bf2f(hv.x), p1 = bf2f(hv.y), p2 = bf2f(hv.z), p3 = bf2f(hv.w);
    acc[0]=s*p0.x; acc[1]=s*p0.y; acc[2]=s*p1.x; acc[3]=s*p1.y;
    acc[4]=s*p2.x; acc[5]=s*p2.y; acc[6]=s*p3.x; acc[7]=s*p3.y; }

  if (lane < cnt){
    wlds4[wid][lane] = make_float4(__expf(v.x - m0), __expf(v.y - m1),
                                   __expf(v.z - m2), __expf(v.w - m3));
    slds[wid][lane] = sj;
  }
  asm volatile("s_waitcnt lgkmcnt(0)" ::: "memory");
  const float* wbase = (const float*)&wlds4[wid][0];
  #pragma unroll 4
  for (int jj = 0; jj < cnt; ++jj){
    float w = wbase[jj * 4 + h];
    int  sv = slds[wid][jj];
    s += w;
    uint4 hb = Hb4[(size_t)sv * 64 + lane];
    float2 p0 = bf2f(hb.x), p1 = bf2f(hb.y), p2 = bf2f(hb.z), p3 = bf2f(hb.w);
    acc[0] = fmaf(w, p0.x, acc[0]); acc[1] = fmaf(w, p0.y, acc[1]);
    acc[2] = fmaf(w, p1.x, acc[2]); acc[3] = fmaf(w, p1.y, acc[3]);
    acc[4] = fmaf(w, p2.x, acc[4]); acc[5] = fmaf(w, p2.y, acc[5]);
    acc[6] = fmaf(w, p3.x, acc[6]); acc[7] = fmaf(w, p3.y, acc[7]);
  }
  asm volatile("s_waitcnt lgkmcnt(0)" ::: "memory");

  // ---- epilogue: normalize, head mean, bias, LN, ReLU, bf16 write ----
  float inv = 1.f / s;
  float t[8];
  #pragma unroll
  for (int i = 0; i < 8; ++i){
    float vv = acc[i] * inv;
    vv += __shfl_xor(vv, 16);
    vv += __shfl_xor(vv, 32);
    t[i] = vv * 0.25f;
  }
  int cb = (lane & 15) * 8;
  float4 b0 = *(const float4*)(bias + cb);
  float4 b1 = *(const float4*)(bias + cb + 4);
  t[0] += b0.x; t[1] += b0.y; t[2] += b0.z; t[3] += b0.w;
  t[4] += b1.x; t[5] += b1.y; t[6] += b1.z; t[7] += b1.w;
  float loc = t[0]+t[1]+t[2]+t[3]+t[4]+t[5]+t[6]+t[7];
  float mu = wsum(loc) * (1.f / 512.f);
  float sq = 0.f;
  #pragma unroll
  for (int i = 0; i < 8; ++i){ t[i] -= mu; sq += t[i] * t[i]; }
  float var = wsum(sq) * (1.f / 512.f);
  float invs = rsqrtf(var + LN_EPS);
  if (lane < 16){
    float4 g0 = *(const float4*)(lng + cb);
    float4 g1 = *(const float4*)(lng + cb + 4);
    float4 o0 = *(const float4*)(lnb + cb);
    float4 o1 = *(const float4*)(lnb + cb + 4);
    float o[8];
    o[0] = fmaxf(t[0]*invs*g0.x + o0.x, 0.f);
    o[1] = fmaxf(t[1]*invs*g0.y + o0.y, 0.f);
    o[2] = fmaxf(t[2]*invs*g0.z + o0.z, 0.f);
    o[3] = fmaxf(t[3]*invs*g0.w + o0.w, 0.f);
    o[4] = fmaxf(t[4]*invs*g1.x + o1.x, 0.f);
    o[5] = fmaxf(t[5]*invs*g1.y + o1.y, 0.f);
    o[6] = fmaxf(t[6]*invs*g1.z + o1.z, 0.f);
    o[7] = fmaxf(t[7]*invs*g1.w + o1.w, 0.f);
    uint4 pb;
    pb.x = pack2bf(o[0], o[1]); pb.y = pack2bf(o[2], o[3]);
    pb.z = pack2bf(o[4], o[5]); pb.w = pack2bf(o[6], o[7]);
    *(uint4*)(XoutBf + (size_t)n * HIDD + cb) = pb;
  }
}

// ---------------- global mean pool (reads bf16) ----------------
__global__ __launch_bounds__(256) void k_pool(const u16* __restrict__ X,
                                              const int* __restrict__ bnd,
                                              float* __restrict__ out){
  int g = blockIdx.x;
  int s = bnd[g], e = bnd[g + 1];
  int c = threadIdx.x & 127, part = threadIdx.x >> 7;
  float acc = 0.f;
  for (int n = s + part; n < e; n += 2) acc += bf1f(X[(size_t)n * HIDD + c]);
  __shared__ float red[256];
  red[threadIdx.x] = acc;
  __syncthreads();
  if (part == 0){
    out[g * HIDD + c] = (red[c] + red[128 + c]) / fmaxf((float)(e - s), 1.f);
  }
}

extern "C" void kernel_launch(void* const* d_in, const int* in_sizes, int n_in,
                              void* d_out, int out_size, void* d_ws, size_t ws_size,
                              hipStream_t stream){
  const float* x        = (const float*)d_in[0];
  const float* ea       = (const float*)d_in[1];
  const float* lin_w[3] = {(const float*)d_in[2], (const float*)d_in[3], (const float*)d_in[4]};
  const float* lin_edge = (const float*)d_in[5];
  const float* att_src  = (const float*)d_in[6];
  const float* att_dst  = (const float*)d_in[7];
  const float* att_edge = (const float*)d_in[8];
  const float* bias     = (const float*)d_in[9];
  const float* lng      = (const float*)d_in[10];
  const float* lnb      = (const float*)d_in[11];
  const int*   eidx     = (const int*)d_in[12];
  const int*   batch    = (const int*)d_in[13];
  const int*   srcp = eidx;
  const int*   dstp = eidx + N_EDG;

  char* ws = (char*)d_ws;
  size_t off = 0;
  auto alloc = [&](size_t bytes)->char*{
    size_t o = off;
    off = (off + bytes + 511) & ~(size_t)511;
    return ws + o;
  };
  int*   cursor   = (int*)  alloc((size_t)N_NODES * 4);
  int*   bnd      = (int*)  alloc((size_t)(NB + 1) * 4);
  float* s_src    = (float*)alloc((size_t)N_NODES * 4 * 4);
  float* s_dst    = (float*)alloc((size_t)N_NODES * 4 * 4);
  float* vfold    = (float*)alloc((size_t)3 * 1152 * 4);
  u32*   erec     = (u32*)  alloc((size_t)N_NODES * PAD * 32);
  u16*   xbf0     = (u16*)  alloc((size_t)N_NODES * EMBD * 2);
  u16*   xbfA     = (u16*)  alloc((size_t)N_NODES * HIDD * 2);
  u16*   xbfB     = (u16*)  alloc((size_t)N_NODES * HIDD * 2);
  u16*   wt0      = (u16*)  alloc((size_t)OUTC * EMBD * 2);
  u16*   wt1      = (u16*)  alloc((size_t)OUTC * HIDD * 2);
  u16*   wt2      = (u16*)  alloc((size_t)OUTC * HIDD * 2);
  u16*   hbuf     = (u16*)  alloc((size_t)N_NODES * OUTC * 2);

  hipMemsetAsync(cursor, 0, (size_t)N_NODES * 4, stream);
  k_setup<<<4420, 256, 0, stream>>>(lin_w[0], lin_w[1], lin_w[2], lin_edge,
                                    att_src, att_dst, att_edge, x, batch,
                                    ea, srcp, dstp, cursor,
                                    vfold, wt0, wt1, wt2, xbf0, bnd, erec);

  const u16* xbcur = xbf0;
  u16* xbout = xbfA;
  for (int L = 0; L < 3; ++L){
    float* vf = vfold + L * 1152;
    const u16* wt = (L == 0) ? wt0 : ((L == 1) ? wt1 : wt2);
    dim3 gg(OUTC / 128, (N_NODES + 63) / 64);
    if (L == 0)
      k_gemm<EMBD><<<gg, 256, 0, stream>>>(xbcur, wt, hbuf, N_NODES, vf,
                                           (float4*)s_src, (float4*)s_dst);
    else
      k_gemm<HIDD><<<gg, 256, 0, stream>>>(xbcur, wt, hbuf, N_NODES, vf,
                                           (float4*)s_src, (float4*)s_dst);
    k_aggr<<<(N_NODES + 3) / 4, 256, 0, stream>>>((const uint4*)hbuf,
        erec, (const float4*)s_src, (const float4*)s_dst,
        cursor, L,
        bias + L * HIDD, lng + L * HIDD, lnb + L * HIDD, xbout);
    xbcur = xbout;
    xbout = (L == 0) ? xbfB : xbfA;
  }

  k_pool<<<NB, 256, 0, stream>>>(xbcur, bnd, (float*)d_out);
}

// Round 16
// 287.906 us; speedup vs baseline: 1.1711x; 1.1711x over previous
//
#include <hip/hip_runtime.h>
#include <math.h>

#define N_NODES 20000
#define N_EDG   320000
#define NB      64
#define EMBD    32
#define HIDD    128
#define NHEAD   4
#define OUTC    512      // H * HID
#define LN_EPS  1e-5f
#define NEG_SLOPE 0.2f
#define PAD     64       // padded-CSR slots per node (max deg ~40 for this dataset)

typedef unsigned int u32;
typedef unsigned short u16;
typedef __attribute__((ext_vector_type(8))) short s16x8;
typedef __attribute__((ext_vector_type(4))) float f32x4;

__device__ __forceinline__ float lrelu(float x){ return x >= 0.f ? x : NEG_SLOPE * x; }

__device__ __forceinline__ float2 bf2f(u32 p){
  float2 r;
  r.x = __uint_as_float(p << 16);
  r.y = __uint_as_float(p & 0xffff0000u);
  return r;
}
__device__ __forceinline__ float bf1f(u16 v){ return __uint_as_float(((u32)v) << 16); }
__device__ __forceinline__ u16 f2bf(float a){
  u32 ua = __float_as_uint(a);
  return (u16)((ua + 0x7fffu + ((ua >> 16) & 1u)) >> 16);
}
__device__ __forceinline__ u32 pack2bf(float a, float b){
  return (u32)f2bf(a) | ((u32)f2bf(b) << 16);
}

// ---------------- fused setup: fold + cvt_w + cvt_x + bounds ----------------
// blocks [0,15): fold; [15,591): cvt_w; [591,3091): cvt_x; [3091,3170): bounds
__global__ __launch_bounds__(256) void k_setup(const float* __restrict__ W0,
                                               const float* __restrict__ W1,
                                               const float* __restrict__ W2,
                                               const float* __restrict__ lin_edge,
                                               const float* __restrict__ att_src,
                                               const float* __restrict__ att_dst,
                                               const float* __restrict__ att_edge,
                                               const float* __restrict__ x,
                                               const int* __restrict__ batch,
                                               float* __restrict__ vfold,
                                               u16* __restrict__ wt0, u16* __restrict__ wt1,
                                               u16* __restrict__ wt2, u16* __restrict__ xb,
                                               int* __restrict__ bnd){
  int b = blockIdx.x;
  if (b < 15){
    int L = b / 5;
    int in_dim = L ? HIDD : EMBD;
    const float* W  = (L == 0) ? W0 : ((L == 1) ? W1 : W2);
    const float* We = lin_edge + (size_t)L * EMBD * OUTC;
    const float* as = att_src + L * 512;
    const float* ad = att_dst + L * 512;
    const float* ae = att_edge + L * 512;
    float* vf = vfold + L * 1152;
    int j = (b % 5) * 256 + threadIdx.x;
    int nsrc = in_dim * NHEAD;
    if (j < nsrc){
      int k = j >> 2, h = j & 3;
      float s = 0.f;
      for (int c = 0; c < HIDD; ++c) s += W[k * OUTC + h * HIDD + c] * as[h * HIDD + c];
      vf[k * 4 + h] = s;
    } else if (j < 2 * nsrc){
      int jj = j - nsrc; int k = jj >> 2, h = jj & 3;
      float s = 0.f;
      for (int c = 0; c < HIDD; ++c) s += W[k * OUTC + h * HIDD + c] * ad[h * HIDD + c];
      vf[512 + k * 4 + h] = s;
    } else if (j < 2 * nsrc + EMBD * NHEAD){
      int jj = j - 2 * nsrc; int k = jj >> 2, h = jj & 3;
      float s = 0.f;
      for (int c = 0; c < HIDD; ++c) s += We[k * OUTC + h * HIDD + c] * ae[h * HIDD + c];
      vf[1024 + k * 4 + h] = s;
    }
  } else if (b < 591){
    int idx = (b - 15) * 256 + threadIdx.x;
    if (idx < 16384){
      int n = idx >> 5, k = idx & 31;
      wt0[idx] = f2bf(W0[(size_t)k * OUTC + n]);
    } else if (idx < 81920){
      int j = idx - 16384; int n = j >> 7, k = j & 127;
      wt1[j] = f2bf(W1[(size_t)k * OUTC + n]);
    } else {
      int j = idx - 81920; int n = j >> 7, k = j & 127;
      wt2[j] = f2bf(W2[(size_t)k * OUTC + n]);
    }
  } else if (b < 3091){
    int i = (b - 591) * 256 + threadIdx.x;
    if (i < N_NODES * EMBD) xb[i] = f2bf(x[i]);
  } else {
    int n = (b - 3091) * 256 + threadIdx.x;
    if (n >= N_NODES) return;
    int bb = batch[n];
    int bp = (n == 0) ? -1 : batch[n - 1];
    for (int g = bp + 1; g <= bb; ++g) bnd[g] = n;
    if (n == N_NODES - 1){
      for (int g = bb + 1; g <= NB; ++g) bnd[g] = N_NODES;
    }
  }
}

// ---------------- padded-CSR scatter + edge projection -> packed 32B record ----------------
// record layout (8 u32): [L0a, L0b, L1a, L1b, L2a, L2b, src, pad], slot = dst*PAD + p
__global__ __launch_bounds__(256) void k_edgescatter(const float* __restrict__ ea,
                                                     const int* __restrict__ src,
                                                     const int* __restrict__ dst,
                                                     int* __restrict__ cursor,
                                                     const float* __restrict__ vfold,
                                                     u32* __restrict__ erec){
  __shared__ float vs[384];
  for (int i = threadIdx.x; i < 384; i += 256)
    vs[i] = vfold[(i >> 7) * 1152 + 1024 + (i & 127)];
  __syncthreads();
  int e = blockIdx.x * blockDim.x + threadIdx.x;
  if (e >= N_EDG) return;
  int d = dst[e];
  int p = atomicAdd(&cursor[d], 1);
  if (p >= PAD) return;   // statistically impossible for this dataset
  float4 a[8];
  const float4* er = (const float4*)(ea + (size_t)e * EMBD);
  #pragma unroll
  for (int i = 0; i < 8; ++i) a[i] = er[i];
  u32 packed[6];
  #pragma unroll
  for (int L = 0; L < 3; ++L){
    const float* v = vs + L * 128;
    float ev[4] = {0,0,0,0};
    #pragma unroll
    for (int q = 0; q < 8; ++q){
      #pragma unroll
      for (int h = 0; h < 4; ++h){
        ev[h] += a[q].x * v[(q*4+0)*4+h] + a[q].y * v[(q*4+1)*4+h]
               + a[q].z * v[(q*4+2)*4+h] + a[q].w * v[(q*4+3)*4+h];
      }
    }
    packed[L*2+0] = pack2bf(ev[0], ev[1]);
    packed[L*2+1] = pack2bf(ev[2], ev[3]);
  }
  u32* rp = erec + ((size_t)d * PAD + p) * 8;
  *(uint4*)rp       = make_uint4(packed[0], packed[1], packed[2], packed[3]);
  *(uint4*)(rp + 4) = make_uint4(packed[4], packed[5], (u32)src[e], 0u);
}

__device__ __forceinline__ float wsum(float v){
  #pragma unroll
  for (int off = 32; off > 0; off >>= 1) v += __shfl_xor(v, off);
  return v;
}
__device__ __forceinline__ float wmax(float v){
  #pragma unroll
  for (int off = 32; off > 0; off >>= 1) v = fmaxf(v, __shfl_xor(v, off));
  return v;
}

// ---------------- MFMA bf16 GEMM + fused per-node s_src/s_dst (reads LDS tile) ----------------
template<int K>
__global__ __launch_bounds__(256) void k_gemm(const u16* __restrict__ Xb,
                                              const u16* __restrict__ Wt,
                                              u16* __restrict__ Hb,
                                              int M,
                                              const float* __restrict__ vf,
                                              float4* __restrict__ s_src,
                                              float4* __restrict__ s_dst){
  const int CH = K + 8;
  __shared__ u16 ldsA[64 * CH];
  __shared__ u16 ldsB[128 * CH];
  int bm = blockIdx.y * 64, bn = blockIdx.x * 128;
  int t = threadIdx.x;
  for (int f = t; f < 64 * (K / 8); f += 256){
    int row = f / (K / 8), c8 = f % (K / 8);
    int gm = bm + row;
    uint4 v = make_uint4(0, 0, 0, 0);
    if (gm < M) v = *(const uint4*)(Xb + (size_t)gm * K + c8 * 8);
    *(uint4*)&ldsA[row * CH + c8 * 8] = v;
  }
  for (int f = t; f < 128 * (K / 8); f += 256){
    int row = f / (K / 8), c8 = f % (K / 8);
    *(uint4*)&ldsB[row * CH + c8 * 8] = *(const uint4*)(Wt + (size_t)(bn + row) * K + c8 * 8);
  }
  __syncthreads();

  int w = t >> 6, lane = t & 63;
  int r = lane & 15, g = lane >> 4;
  f32x4 acc[8];
  #pragma unroll
  for (int i = 0; i < 8; ++i) acc[i] = (f32x4){0.f, 0.f, 0.f, 0.f};
  const u16* pa = &ldsA[(w * 16 + r) * CH + g * 8];
  #pragma unroll
  for (int k0 = 0; k0 < K; k0 += 32){
    s16x8 a = *(const s16x8*)(pa + k0);
    #pragma unroll
    for (int nf = 0; nf < 8; ++nf){
      s16x8 b = *(const s16x8*)(&ldsB[(nf * 16 + r) * CH + k0 + g * 8]);
      acc[nf] = __builtin_amdgcn_mfma_f32_16x16x32_bf16(a, b, acc[nf], 0, 0, 0);
    }
  }
  #pragma unroll
  for (int nf = 0; nf < 8; ++nf){
    #pragma unroll
    for (int i = 0; i < 4; ++i){
      int gm = bm + w * 16 + g * 4 + i;
      if (gm < M) Hb[(size_t)gm * OUTC + bn + nf * 16 + r] = f2bf(acc[nf][i]);
    }
  }

  // fused nodelin: column-0 blocks compute s_src/s_dst for their 64 rows, from LDS tile
  if (blockIdx.x == 0 && t < 64){
    int nn = bm + t;
    if (nn < M){
      float a[4] = {0,0,0,0}, d[4] = {0,0,0,0};
      const u16* xr = &ldsA[t * CH];
      #pragma unroll 8
      for (int k = 0; k < K; ++k){
        float xv = bf1f(xr[k]);
        #pragma unroll
        for (int h = 0; h < 4; ++h){
          a[h] = fmaf(xv, vf[k*4+h], a[h]);
          d[h] = fmaf(xv, vf[512+k*4+h], d[h]);
        }
      }
      s_src[nn] = make_float4(a[0], a[1], a[2], a[3]);
      s_dst[nn] = make_float4(d[0], d[1], d[2], d[3]);
    }
  }
}

// ---------------- wave-per-node aggregation: padded CSR, single-tile fast path ----------------
__global__ __launch_bounds__(256) void k_aggr(const uint4* __restrict__ Hb4,
                                              const u32* __restrict__ erec,
                                              const float4* __restrict__ s_src4,
                                              const float4* __restrict__ s_dst4,
                                              const int* __restrict__ cursor,
                                              int L,
                                              const float* __restrict__ bias,
                                              const float* __restrict__ lng,
                                              const float* __restrict__ lnb,
                                              u16* __restrict__ XoutBf){
  __shared__ float4 wlds4[4][64];
  __shared__ int    slds[4][64];
  int wid  = threadIdx.x >> 6;
  int lane = threadIdx.x & 63;
  int n = blockIdx.x * 4 + wid;
  if (n >= N_NODES) return;
  int h = lane >> 4;
  int degn = cursor[n];
  int cnt = min(degn, PAD);

  float4 dd = s_dst4[n];
  float4 sn = s_src4[n];
  uint4 hv = Hb4[(size_t)n * 64 + lane];    // own row (prefetch)

  // ---- logits in registers, per-head max + ev-sum (lane-parallel) ----
  float4 v = make_float4(-1e30f, -1e30f, -1e30f, -1e30f);
  float4 evv = make_float4(0.f, 0.f, 0.f, 0.f);
  int sj = 0;
  if (lane < cnt){
    const u32* rp = erec + ((size_t)n * PAD + lane) * 8;
    uint2 ep = *(const uint2*)(rp + 2 * L);
    sj = (int)rp[6];
    float2 e01 = bf2f(ep.x), e23 = bf2f(ep.y);
    evv = make_float4(e01.x, e01.y, e23.x, e23.y);
    float4 ss = s_src4[sj];
    v.x = lrelu(ss.x + dd.x + evv.x);
    v.y = lrelu(ss.y + dd.y + evv.y);
    v.z = lrelu(ss.z + dd.z + evv.z);
    v.w = lrelu(ss.w + dd.w + evv.w);
  }
  float m0 = wmax(v.x), m1 = wmax(v.y), m2 = wmax(v.z), m3 = wmax(v.w);
  float pv0 = wsum(evv.x), pv1 = wsum(evv.y), pv2 = wsum(evv.z), pv3 = wsum(evv.w);
  float invd = 1.f / fmaxf((float)degn, 1.f);
  float ll0 = lrelu(sn.x + dd.x + pv0 * invd);
  float ll1 = lrelu(sn.y + dd.y + pv1 * invd);
  float ll2 = lrelu(sn.z + dd.z + pv2 * invd);
  float ll3 = lrelu(sn.w + dd.w + pv3 * invd);
  m0 = fmaxf(m0, ll0); m1 = fmaxf(m1, ll1);
  m2 = fmaxf(m2, ll2); m3 = fmaxf(m3, ll3);
  float mh  = (h == 0) ? m0 : ((h == 1) ? m1 : ((h == 2) ? m2 : m3));
  float llh = (h == 0) ? ll0 : ((h == 1) ? ll1 : ((h == 2) ? ll2 : ll3));

  float s = __expf(llh - mh);
  float acc[8];
  { float2 p0 = bf2f(hv.x), p1 = bf2f(hv.y), p2 = bf2f(hv.z), p3 = bf2f(hv.w);
    acc[0]=s*p0.x; acc[1]=s*p0.y; acc[2]=s*p1.x; acc[3]=s*p1.y;
    acc[4]=s*p2.x; acc[5]=s*p2.y; acc[6]=s*p3.x; acc[7]=s*p3.y; }

  if (lane < cnt){
    wlds4[wid][lane] = make_float4(__expf(v.x - m0), __expf(v.y - m1),
                                   __expf(v.z - m2), __expf(v.w - m3));
    slds[wid][lane] = sj;
  }
  asm volatile("s_waitcnt lgkmcnt(0)" ::: "memory");
  const float* wbase = (const float*)&wlds4[wid][0];
  #pragma unroll 4
  for (int jj = 0; jj < cnt; ++jj){
    float w = wbase[jj * 4 + h];
    int  sv = slds[wid][jj];
    s += w;
    uint4 hb = Hb4[(size_t)sv * 64 + lane];
    float2 p0 = bf2f(hb.x), p1 = bf2f(hb.y), p2 = bf2f(hb.z), p3 = bf2f(hb.w);
    acc[0] = fmaf(w, p0.x, acc[0]); acc[1] = fmaf(w, p0.y, acc[1]);
    acc[2] = fmaf(w, p1.x, acc[2]); acc[3] = fmaf(w, p1.y, acc[3]);
    acc[4] = fmaf(w, p2.x, acc[4]); acc[5] = fmaf(w, p2.y, acc[5]);
    acc[6] = fmaf(w, p3.x, acc[6]); acc[7] = fmaf(w, p3.y, acc[7]);
  }
  asm volatile("s_waitcnt lgkmcnt(0)" ::: "memory");

  // ---- epilogue: normalize, head mean, bias, LN, ReLU, bf16 write ----
  float inv = 1.f / s;
  float t[8];
  #pragma unroll
  for (int i = 0; i < 8; ++i){
    float vv = acc[i] * inv;
    vv += __shfl_xor(vv, 16);
    vv += __shfl_xor(vv, 32);
    t[i] = vv * 0.25f;
  }
  int cb = (lane & 15) * 8;
  float4 b0 = *(const float4*)(bias + cb);
  float4 b1 = *(const float4*)(bias + cb + 4);
  t[0] += b0.x; t[1] += b0.y; t[2] += b0.z; t[3] += b0.w;
  t[4] += b1.x; t[5] += b1.y; t[6] += b1.z; t[7] += b1.w;
  float loc = t[0]+t[1]+t[2]+t[3]+t[4]+t[5]+t[6]+t[7];
  float mu = wsum(loc) * (1.f / 512.f);
  float sq = 0.f;
  #pragma unroll
  for (int i = 0; i < 8; ++i){ t[i] -= mu; sq += t[i] * t[i]; }
  float var = wsum(sq) * (1.f / 512.f);
  float invs = rsqrtf(var + LN_EPS);
  if (lane < 16){
    float4 g0 = *(const float4*)(lng + cb);
    float4 g1 = *(const float4*)(lng + cb + 4);
    float4 o0 = *(const float4*)(lnb + cb);
    float4 o1 = *(const float4*)(lnb + cb + 4);
    float o[8];
    o[0] = fmaxf(t[0]*invs*g0.x + o0.x, 0.f);
    o[1] = fmaxf(t[1]*invs*g0.y + o0.y, 0.f);
    o[2] = fmaxf(t[2]*invs*g0.z + o0.z, 0.f);
    o[3] = fmaxf(t[3]*invs*g0.w + o0.w, 0.f);
    o[4] = fmaxf(t[4]*invs*g1.x + o1.x, 0.f);
    o[5] = fmaxf(t[5]*invs*g1.y + o1.y, 0.f);
    o[6] = fmaxf(t[6]*invs*g1.z + o1.z, 0.f);
    o[7] = fmaxf(t[7]*invs*g1.w + o1.w, 0.f);
    uint4 pb;
    pb.x = pack2bf(o[0], o[1]); pb.y = pack2bf(o[2], o[3]);
    pb.z = pack2bf(o[4], o[5]); pb.w = pack2bf(o[6], o[7]);
    *(uint4*)(XoutBf + (size_t)n * HIDD + cb) = pb;
  }
}

// ---------------- global mean pool (reads bf16) ----------------
__global__ __launch_bounds__(256) void k_pool(const u16* __restrict__ X,
                                              const int* __restrict__ bnd,
                                              float* __restrict__ out){
  int g = blockIdx.x;
  int s = bnd[g], e = bnd[g + 1];
  int c = threadIdx.x & 127, part = threadIdx.x >> 7;
  float acc = 0.f;
  for (int n = s + part; n < e; n += 2) acc += bf1f(X[(size_t)n * HIDD + c]);
  __shared__ float red[256];
  red[threadIdx.x] = acc;
  __syncthreads();
  if (part == 0){
    out[g * HIDD + c] = (red[c] + red[128 + c]) / fmaxf((float)(e - s), 1.f);
  }
}

extern "C" void kernel_launch(void* const* d_in, const int* in_sizes, int n_in,
                              void* d_out, int out_size, void* d_ws, size_t ws_size,
                              hipStream_t stream){
  const float* x        = (const float*)d_in[0];
  const float* ea       = (const float*)d_in[1];
  const float* lin_w[3] = {(const float*)d_in[2], (const float*)d_in[3], (const float*)d_in[4]};
  const float* lin_edge = (const float*)d_in[5];
  const float* att_src  = (const float*)d_in[6];
  const float* att_dst  = (const float*)d_in[7];
  const float* att_edge = (const float*)d_in[8];
  const float* bias     = (const float*)d_in[9];
  const float* lng      = (const float*)d_in[10];
  const float* lnb      = (const float*)d_in[11];
  const int*   eidx     = (const int*)d_in[12];
  const int*   batch    = (const int*)d_in[13];
  const int*   srcp = eidx;
  const int*   dstp = eidx + N_EDG;

  char* ws = (char*)d_ws;
  size_t off = 0;
  auto alloc = [&](size_t bytes)->char*{
    size_t o = off;
    off = (off + bytes + 511) & ~(size_t)511;
    return ws + o;
  };
  int*   cursor   = (int*)  alloc((size_t)N_NODES * 4);
  int*   bnd      = (int*)  alloc((size_t)(NB + 1) * 4);
  float* s_src    = (float*)alloc((size_t)N_NODES * 4 * 4);
  float* s_dst    = (float*)alloc((size_t)N_NODES * 4 * 4);
  float* vfold    = (float*)alloc((size_t)3 * 1152 * 4);
  u32*   erec     = (u32*)  alloc((size_t)N_NODES * PAD * 32);
  u16*   xbf0     = (u16*)  alloc((size_t)N_NODES * EMBD * 2);
  u16*   xbfA     = (u16*)  alloc((size_t)N_NODES * HIDD * 2);
  u16*   xbfB     = (u16*)  alloc((size_t)N_NODES * HIDD * 2);
  u16*   wt0      = (u16*)  alloc((size_t)OUTC * EMBD * 2);
  u16*   wt1      = (u16*)  alloc((size_t)OUTC * HIDD * 2);
  u16*   wt2      = (u16*)  alloc((size_t)OUTC * HIDD * 2);
  u16*   hbuf     = (u16*)  alloc((size_t)N_NODES * OUTC * 2);

  hipMemsetAsync(cursor, 0, (size_t)N_NODES * 4, stream);
  k_setup<<<3170, 256, 0, stream>>>(lin_w[0], lin_w[1], lin_w[2], lin_edge,
                                    att_src, att_dst, att_edge, x, batch,
                                    vfold, wt0, wt1, wt2, xbf0, bnd);
  k_edgescatter<<<(N_EDG + 255) / 256, 256, 0, stream>>>(ea, srcp, dstp, cursor,
                                                         vfold, erec);

  const u16* xbcur = xbf0;
  u16* xbout = xbfA;
  for (int L = 0; L < 3; ++L){
    float* vf = vfold + L * 1152;
    const u16* wt = (L == 0) ? wt0 : ((L == 1) ? wt1 : wt2);
    dim3 gg(OUTC / 128, (N_NODES + 63) / 64);
    if (L == 0)
      k_gemm<EMBD><<<gg, 256, 0, stream>>>(xbcur, wt, hbuf, N_NODES, vf,
                                           (float4*)s_src, (float4*)s_dst);
    else
      k_gemm<HIDD><<<gg, 256, 0, stream>>>(xbcur, wt, hbuf, N_NODES, vf,
                                           (float4*)s_src, (float4*)s_dst);
    k_aggr<<<(N_NODES + 3) / 4, 256, 0, stream>>>((const uint4*)hbuf,
        erec, (const float4*)s_src, (const float4*)s_dst,
        cursor, L,
        bias + L * HIDD, lng + L * HIDD, lnb + L * HIDD, xbout);
    xbcur = xbout;
    xbout = (L == 0) ? xbfB : xbfA;
  }

  k_pool<<<NB, 256, 0, stream>>>(xbcur, bnd, (float*)d_out);
}

// Round 17
// 223.403 us; speedup vs baseline: 1.5093x; 1.2887x over previous
//
#include <hip/hip_runtime.h>
#include <math.h>

#define N_NODES 20000
#define N_EDG   320000
#define NB      64
#define EMBD    32
#define HIDD    128
#define NHEAD   4
#define OUTC    512      // H * HID
#define LN_EPS  1e-5f
#define NEG_SLOPE 0.2f
#define PAD     64       // padded-CSR slots per node (max deg ~40 for this dataset)

typedef unsigned int u32;
typedef unsigned short u16;
typedef __attribute__((ext_vector_type(8))) short s16x8;
typedef __attribute__((ext_vector_type(4))) float f32x4;

__device__ __forceinline__ float lrelu(float x){ return x >= 0.f ? x : NEG_SLOPE * x; }

__device__ __forceinline__ float2 bf2f(u32 p){
  float2 r;
  r.x = __uint_as_float(p << 16);
  r.y = __uint_as_float(p & 0xffff0000u);
  return r;
}
__device__ __forceinline__ float bf1f(u16 v){ return __uint_as_float(((u32)v) << 16); }
__device__ __forceinline__ u16 f2bf(float a){
  u32 ua = __float_as_uint(a);
  return (u16)((ua + 0x7fffu + ((ua >> 16) & 1u)) >> 16);
}
__device__ __forceinline__ u32 pack2bf(float a, float b){
  return (u32)f2bf(a) | ((u32)f2bf(b) << 16);
}

__device__ __forceinline__ float wsum(float v){
  #pragma unroll
  for (int off = 32; off > 0; off >>= 1) v += __shfl_xor(v, off);
  return v;
}
__device__ __forceinline__ float wmax(float v){
  #pragma unroll
  for (int off = 32; off > 0; off >>= 1) v = fmaxf(v, __shfl_xor(v, off));
  return v;
}

// ---------------- fused setup: fold + stacked-W cvt + cvt_x + bounds ----------------
// blocks [0,15): fold; [15,591): wstk cvt; [591,3091): cvt_x; [3091,3170): bounds
// wstk layouts (bf16, out-ch major): wstk0 [128][128] f=h*32+k; wstk1/2 [128][512] f=h*128+k
__global__ __launch_bounds__(256) void k_setup(const float* __restrict__ W0,
                                               const float* __restrict__ W1,
                                               const float* __restrict__ W2,
                                               const float* __restrict__ lin_edge,
                                               const float* __restrict__ att_src,
                                               const float* __restrict__ att_dst,
                                               const float* __restrict__ att_edge,
                                               const float* __restrict__ x,
                                               const int* __restrict__ batch,
                                               float* __restrict__ vfold,
                                               u16* __restrict__ wstk0, u16* __restrict__ wstk1,
                                               u16* __restrict__ wstk2, u16* __restrict__ xb,
                                               int* __restrict__ bnd){
  int b = blockIdx.x;
  if (b < 15){
    int L = b / 5;
    int in_dim = L ? HIDD : EMBD;
    const float* W  = (L == 0) ? W0 : ((L == 1) ? W1 : W2);
    const float* We = lin_edge + (size_t)L * EMBD * OUTC;
    const float* as = att_src + L * 512;
    const float* ad = att_dst + L * 512;
    const float* ae = att_edge + L * 512;
    float* vf = vfold + L * 1152;
    int j = (b % 5) * 256 + threadIdx.x;
    int nsrc = in_dim * NHEAD;
    if (j < nsrc){
      int k = j >> 2, h = j & 3;
      float s = 0.f;
      for (int c = 0; c < HIDD; ++c) s += W[k * OUTC + h * HIDD + c] * as[h * HIDD + c];
      vf[k * 4 + h] = s;
    } else if (j < 2 * nsrc){
      int jj = j - nsrc; int k = jj >> 2, h = jj & 3;
      float s = 0.f;
      for (int c = 0; c < HIDD; ++c) s += W[k * OUTC + h * HIDD + c] * ad[h * HIDD + c];
      vf[512 + k * 4 + h] = s;
    } else if (j < 2 * nsrc + EMBD * NHEAD){
      int jj = j - 2 * nsrc; int k = jj >> 2, h = jj & 3;
      float s = 0.f;
      for (int c = 0; c < HIDD; ++c) s += We[k * OUTC + h * HIDD + c] * ae[h * HIDD + c];
      vf[1024 + k * 4 + h] = s;
    }
  } else if (b < 591){
    int idx = (b - 15) * 256 + threadIdx.x;
    if (idx < 16384){
      int c = idx >> 7, f = idx & 127;
      int hh = f >> 5, k = f & 31;
      wstk0[idx] = f2bf(W0[(size_t)k * OUTC + hh * HIDD + c] * 0.25f);
    } else if (idx < 81920){
      int j = idx - 16384;
      int c = j >> 9, f = j & 511;
      int hh = f >> 7, k = f & 127;
      wstk1[j] = f2bf(W1[(size_t)k * OUTC + hh * HIDD + c] * 0.25f);
    } else if (idx < 147456){
      int j = idx - 81920;
      int c = j >> 9, f = j & 511;
      int hh = f >> 7, k = f & 127;
      wstk2[j] = f2bf(W2[(size_t)k * OUTC + hh * HIDD + c] * 0.25f);
    }
  } else if (b < 3091){
    int i = (b - 591) * 256 + threadIdx.x;
    if (i < N_NODES * EMBD) xb[i] = f2bf(x[i]);
  } else {
    int n = (b - 3091) * 256 + threadIdx.x;
    if (n >= N_NODES) return;
    int bb = batch[n];
    int bp = (n == 0) ? -1 : batch[n - 1];
    for (int g = bp + 1; g <= bb; ++g) bnd[g] = n;
    if (n == N_NODES - 1){
      for (int g = bb + 1; g <= NB; ++g) bnd[g] = N_NODES;
    }
  }
}

// ---------------- padded-CSR scatter + edge projection + layer-0 nodelin ----------------
// blocks [0,1250): edges; [1250,1329): layer-0 s_src/s_dst from f32 x
__global__ __launch_bounds__(256) void k_edgescatter(const float* __restrict__ ea,
                                                     const int* __restrict__ src,
                                                     const int* __restrict__ dst,
                                                     int* __restrict__ cursor,
                                                     const float* __restrict__ vfold,
                                                     u32* __restrict__ erec,
                                                     const float* __restrict__ x,
                                                     float4* __restrict__ s_src,
                                                     float4* __restrict__ s_dst){
  __shared__ float vsh[1024];
  int b = blockIdx.x;
  if (b < 1250){
    for (int i = threadIdx.x; i < 384; i += 256)
      vsh[i] = vfold[(i >> 7) * 1152 + 1024 + (i & 127)];
    __syncthreads();
    int e = b * 256 + threadIdx.x;
    if (e >= N_EDG) return;
    int d = dst[e];
    int p = atomicAdd(&cursor[d], 1);
    if (p >= PAD) return;
    float4 a[8];
    const float4* er = (const float4*)(ea + (size_t)e * EMBD);
    #pragma unroll
    for (int i = 0; i < 8; ++i) a[i] = er[i];
    u32 packed[6];
    #pragma unroll
    for (int L = 0; L < 3; ++L){
      const float* v = vsh + L * 128;
      float ev[4] = {0,0,0,0};
      #pragma unroll
      for (int q = 0; q < 8; ++q){
        #pragma unroll
        for (int h = 0; h < 4; ++h){
          ev[h] += a[q].x * v[(q*4+0)*4+h] + a[q].y * v[(q*4+1)*4+h]
                 + a[q].z * v[(q*4+2)*4+h] + a[q].w * v[(q*4+3)*4+h];
        }
      }
      packed[L*2+0] = pack2bf(ev[0], ev[1]);
      packed[L*2+1] = pack2bf(ev[2], ev[3]);
    }
    u32* rp = erec + ((size_t)d * PAD + p) * 8;
    *(uint4*)rp       = make_uint4(packed[0], packed[1], packed[2], packed[3]);
    *(uint4*)(rp + 4) = make_uint4(packed[4], packed[5], (u32)src[e], 0u);
  } else {
    for (int i = threadIdx.x; i < 1024; i += 256) vsh[i] = vfold[i];
    __syncthreads();
    int n = (b - 1250) * 256 + threadIdx.x;
    if (n >= N_NODES) return;
    float a[4] = {0,0,0,0}, d[4] = {0,0,0,0};
    const float* xr = x + (size_t)n * EMBD;
    #pragma unroll
    for (int k4 = 0; k4 < EMBD; k4 += 4){
      float4 xv = *(const float4*)(xr + k4);
      #pragma unroll
      for (int h = 0; h < 4; ++h){
        a[h] += xv.x * vsh[(k4+0)*4+h] + xv.y * vsh[(k4+1)*4+h]
              + xv.z * vsh[(k4+2)*4+h] + xv.w * vsh[(k4+3)*4+h];
        d[h] += xv.x * vsh[512+(k4+0)*4+h] + xv.y * vsh[512+(k4+1)*4+h]
              + xv.z * vsh[512+(k4+2)*4+h] + xv.w * vsh[512+(k4+3)*4+h];
      }
    }
    s_src[n] = make_float4(a[0], a[1], a[2], a[3]);
    s_dst[n] = make_float4(d[0], d[1], d[2], d[3]);
  }
}

// ---------------- x-space aggregation: agg[n][h*IN+k] = softmax-weighted sum of x rows ----------------
template<int IN>   // 32 (layer 0) or 128
__global__ __launch_bounds__(256) void k_aggr(const u32* __restrict__ Xw,   // bf16 rows, IN/2 words
                                              const u32* __restrict__ erec,
                                              const float4* __restrict__ s_src4,
                                              const float4* __restrict__ s_dst4,
                                              const int* __restrict__ cursor,
                                              int L,
                                              u32* __restrict__ agg){      // [N, 2*IN] words
  const int NW = IN / 2;     // words per x row
  const int G  = 64 / NW;    // edges processed per iteration
  __shared__ float4 wlds4[4][64];
  __shared__ int    slds[4][64];
  int wid  = threadIdx.x >> 6;
  int lane = threadIdx.x & 63;
  int n = blockIdx.x * 4 + wid;
  if (n >= N_NODES) return;
  int degn = cursor[n];
  int cnt = min(degn, PAD);

  float4 dd = s_dst4[n];
  float4 sn = s_src4[n];

  // ---- logit phase: lane-parallel, registers only ----
  float4 v = make_float4(-1e30f, -1e30f, -1e30f, -1e30f);
  float4 evv = make_float4(0.f, 0.f, 0.f, 0.f);
  int sj = 0;
  if (lane < cnt){
    const u32* rp = erec + ((size_t)n * PAD + lane) * 8;
    uint2 ep = *(const uint2*)(rp + 2 * L);
    sj = (int)rp[6];
    float2 e01 = bf2f(ep.x), e23 = bf2f(ep.y);
    evv = make_float4(e01.x, e01.y, e23.x, e23.y);
    float4 ss = s_src4[sj];
    v.x = lrelu(ss.x + dd.x + evv.x);
    v.y = lrelu(ss.y + dd.y + evv.y);
    v.z = lrelu(ss.z + dd.z + evv.z);
    v.w = lrelu(ss.w + dd.w + evv.w);
  }
  float m0 = wmax(v.x), m1 = wmax(v.y), m2 = wmax(v.z), m3 = wmax(v.w);
  float pv0 = wsum(evv.x), pv1 = wsum(evv.y), pv2 = wsum(evv.z), pv3 = wsum(evv.w);
  float invd = 1.f / fmaxf((float)degn, 1.f);
  float ll0 = lrelu(sn.x + dd.x + pv0 * invd);
  float ll1 = lrelu(sn.y + dd.y + pv1 * invd);
  float ll2 = lrelu(sn.z + dd.z + pv2 * invd);
  float ll3 = lrelu(sn.w + dd.w + pv3 * invd);
  m0 = fmaxf(m0, ll0); m1 = fmaxf(m1, ll1);
  m2 = fmaxf(m2, ll2); m3 = fmaxf(m3, ll3);
  float e0 = (lane < cnt) ? __expf(v.x - m0) : 0.f;
  float e1 = (lane < cnt) ? __expf(v.y - m1) : 0.f;
  float e2 = (lane < cnt) ? __expf(v.z - m2) : 0.f;
  float e3 = (lane < cnt) ? __expf(v.w - m3) : 0.f;
  float ws0 = __expf(ll0 - m0), ws1 = __expf(ll1 - m1);
  float ws2 = __expf(ll2 - m2), ws3 = __expf(ll3 - m3);
  float i0 = 1.f / (wsum(e0) + ws0);
  float i1 = 1.f / (wsum(e1) + ws1);
  float i2 = 1.f / (wsum(e2) + ws2);
  float i3 = 1.f / (wsum(e3) + ws3);
  if (lane < cnt){
    wlds4[wid][lane] = make_float4(e0, e1, e2, e3);
    slds[wid][lane] = sj;
  }
  asm volatile("s_waitcnt lgkmcnt(0)" ::: "memory");

  // ---- gather phase: x-space rows ----
  int wi  = lane & (NW - 1);
  int grp = lane / NW;
  float self = (grp == 0) ? 1.f : 0.f;
  float acc[8];     // [head][2ch]
  {
    float2 xx = bf2f(Xw[(size_t)n * NW + wi]);
    acc[0] = self * ws0 * xx.x; acc[1] = self * ws0 * xx.y;
    acc[2] = self * ws1 * xx.x; acc[3] = self * ws1 * xx.y;
    acc[4] = self * ws2 * xx.x; acc[5] = self * ws2 * xx.y;
    acc[6] = self * ws3 * xx.x; acc[7] = self * ws3 * xx.y;
  }
  const float* wbase = (const float*)&wlds4[wid][0];
  #pragma unroll 4
  for (int jj = 0; jj < cnt; jj += G){
    int j = jj + grp;
    if (j < cnt){
      float w0 = wbase[j * 4 + 0];
      float w1 = wbase[j * 4 + 1];
      float w2 = wbase[j * 4 + 2];
      float w3 = wbase[j * 4 + 3];
      int  sv = slds[wid][j];
      float2 xx = bf2f(Xw[(size_t)sv * NW + wi]);
      acc[0] = fmaf(w0, xx.x, acc[0]); acc[1] = fmaf(w0, xx.y, acc[1]);
      acc[2] = fmaf(w1, xx.x, acc[2]); acc[3] = fmaf(w1, xx.y, acc[3]);
      acc[4] = fmaf(w2, xx.x, acc[4]); acc[5] = fmaf(w2, xx.y, acc[5]);
      acc[6] = fmaf(w3, xx.x, acc[6]); acc[7] = fmaf(w3, xx.y, acc[7]);
    }
  }
  asm volatile("s_waitcnt lgkmcnt(0)" ::: "memory");
  if (G > 1){
    #pragma unroll
    for (int q = 0; q < 8; ++q){
      acc[q] += __shfl_xor(acc[q], 16);
      acc[q] += __shfl_xor(acc[q], 32);
    }
  }
  if (grp == 0){
    u32* ar = agg + (size_t)n * (2 * IN);
    ar[0 * NW + wi] = pack2bf(acc[0] * i0, acc[1] * i0);
    ar[1 * NW + wi] = pack2bf(acc[2] * i1, acc[3] * i1);
    ar[2 * NW + wi] = pack2bf(acc[4] * i2, acc[5] * i2);
    ar[3 * NW + wi] = pack2bf(acc[6] * i3, acc[7] * i3);
  }
}

// ---------------- stacked-head GEMM + bias + LN + ReLU + next-layer logits ----------------
// C[n][c] = sum_f agg[n][f] * Wstk[c][f]  (Wstk pre-scaled by 1/4)
template<int KF, int NEXT>   // KF = 128 or 512
__global__ __launch_bounds__(256) void k_gemmLN(const u16* __restrict__ Ab,   // agg [N,KF] bf16
                                                const u16* __restrict__ Bt,   // [128][KF] bf16
                                                const float* __restrict__ bias,
                                                const float* __restrict__ lng,
                                                const float* __restrict__ lnb,
                                                const float* __restrict__ vfN, // next vfold (1024 f) or junk
                                                u16* __restrict__ Xout,       // [N,128] bf16
                                                float4* __restrict__ s_srcN,
                                                float4* __restrict__ s_dstN,
                                                int M){
  const int CH = 136;   // BK=128 + 8 pad
  __shared__ u16 ldsA[64 * CH];
  __shared__ u16 ldsB[128 * CH];
  __shared__ float prm[384 + 1024];
  int bm = blockIdx.x * 64;
  int t = threadIdx.x;
  for (int i = t; i < 384; i += 256){
    const float* sp = (i < 128) ? bias : ((i < 256) ? lng : lnb);
    prm[i] = sp[i & 127];
  }
  if (NEXT){
    for (int i = t; i < 1024; i += 256) prm[384 + i] = vfN[i];
  }
  int w = t >> 6, lane = t & 63, r = lane & 15, g = lane >> 4;
  f32x4 acc[8];
  #pragma unroll
  for (int i = 0; i < 8; ++i) acc[i] = (f32x4){0.f, 0.f, 0.f, 0.f};

  for (int kt = 0; kt < KF; kt += 128){
    for (int f = t; f < 64 * 16; f += 256){
      int row = f >> 4, c8 = f & 15;
      int gm = bm + row;
      uint4 vv = make_uint4(0, 0, 0, 0);
      if (gm < M) vv = *(const uint4*)(Ab + (size_t)gm * KF + kt + c8 * 8);
      *(uint4*)&ldsA[row * CH + c8 * 8] = vv;
    }
    for (int f = t; f < 128 * 16; f += 256){
      int row = f >> 4, c8 = f & 15;
      *(uint4*)&ldsB[row * CH + c8 * 8] = *(const uint4*)(Bt + (size_t)row * KF + kt + c8 * 8);
    }
    __syncthreads();
    #pragma unroll
    for (int k0 = 0; k0 < 128; k0 += 32){
      s16x8 a = *(const s16x8*)(&ldsA[(w * 16 + r) * CH + k0 + g * 8]);
      #pragma unroll
      for (int nf = 0; nf < 8; ++nf){
        s16x8 b = *(const s16x8*)(&ldsB[(nf * 16 + r) * CH + k0 + g * 8]);
        acc[nf] = __builtin_amdgcn_mfma_f32_16x16x32_bf16(a, b, acc[nf], 0, 0, 0);
      }
    }
    __syncthreads();
  }

  // epilogue: row gm = bm + w*16 + g*4 + i; channel = nf*16 + r (16 r-lanes per row)
  #pragma unroll
  for (int i = 0; i < 4; ++i){
    int gm = bm + w * 16 + g * 4 + i;
    float tt[8];
    float rs = 0.f;
    #pragma unroll
    for (int nf = 0; nf < 8; ++nf){
      tt[nf] = acc[nf][i] + prm[nf * 16 + r];
      rs += tt[nf];
    }
    rs += __shfl_xor(rs, 1); rs += __shfl_xor(rs, 2);
    rs += __shfl_xor(rs, 4); rs += __shfl_xor(rs, 8);
    float mu = rs * (1.f / 128.f);
    float sq = 0.f;
    #pragma unroll
    for (int nf = 0; nf < 8; ++nf){ tt[nf] -= mu; sq += tt[nf] * tt[nf]; }
    sq += __shfl_xor(sq, 1); sq += __shfl_xor(sq, 2);
    sq += __shfl_xor(sq, 4); sq += __shfl_xor(sq, 8);
    float invs = rsqrtf(sq * (1.f / 128.f) + LN_EPS);
    float pa0 = 0.f, pa1 = 0.f, pa2 = 0.f, pa3 = 0.f;
    float pd0 = 0.f, pd1 = 0.f, pd2 = 0.f, pd3 = 0.f;
    #pragma unroll
    for (int nf = 0; nf < 8; ++nf){
      int ch = nf * 16 + r;
      float o = fmaxf(tt[nf] * invs * prm[128 + ch] + prm[256 + ch], 0.f);
      if (gm < M) Xout[(size_t)gm * HIDD + ch] = f2bf(o);
      if (NEXT){
        pa0 = fmaf(o, prm[384 + ch * 4 + 0], pa0);
        pa1 = fmaf(o, prm[384 + ch * 4 + 1], pa1);
        pa2 = fmaf(o, prm[384 + ch * 4 + 2], pa2);
        pa3 = fmaf(o, prm[384 + ch * 4 + 3], pa3);
        pd0 = fmaf(o, prm[384 + 512 + ch * 4 + 0], pd0);
        pd1 = fmaf(o, prm[384 + 512 + ch * 4 + 1], pd1);
        pd2 = fmaf(o, prm[384 + 512 + ch * 4 + 2], pd2);
        pd3 = fmaf(o, prm[384 + 512 + ch * 4 + 3], pd3);
      }
    }
    if (NEXT){
      #pragma unroll
      for (int m = 1; m < 16; m <<= 1){
        pa0 += __shfl_xor(pa0, m); pa1 += __shfl_xor(pa1, m);
        pa2 += __shfl_xor(pa2, m); pa3 += __shfl_xor(pa3, m);
        pd0 += __shfl_xor(pd0, m); pd1 += __shfl_xor(pd1, m);
        pd2 += __shfl_xor(pd2, m); pd3 += __shfl_xor(pd3, m);
      }
      if (r == 0 && gm < M){
        s_srcN[gm] = make_float4(pa0, pa1, pa2, pa3);
        s_dstN[gm] = make_float4(pd0, pd1, pd2, pd3);
      }
    }
  }
}

// ---------------- global mean pool (reads bf16) ----------------
__global__ __launch_bounds__(256) void k_pool(const u16* __restrict__ X,
                                              const int* __restrict__ bnd,
                                              float* __restrict__ out){
  int g = blockIdx.x;
  int s = bnd[g], e = bnd[g + 1];
  int c = threadIdx.x & 127, part = threadIdx.x >> 7;
  float acc = 0.f;
  for (int n = s + part; n < e; n += 2) acc += bf1f(X[(size_t)n * HIDD + c]);
  __shared__ float red[256];
  red[threadIdx.x] = acc;
  __syncthreads();
  if (part == 0){
    out[g * HIDD + c] = (red[c] + red[128 + c]) / fmaxf((float)(e - s), 1.f);
  }
}

extern "C" void kernel_launch(void* const* d_in, const int* in_sizes, int n_in,
                              void* d_out, int out_size, void* d_ws, size_t ws_size,
                              hipStream_t stream){
  const float* x        = (const float*)d_in[0];
  const float* ea       = (const float*)d_in[1];
  const float* lin_w[3] = {(const float*)d_in[2], (const float*)d_in[3], (const float*)d_in[4]};
  const float* lin_edge = (const float*)d_in[5];
  const float* att_src  = (const float*)d_in[6];
  const float* att_dst  = (const float*)d_in[7];
  const float* att_edge = (const float*)d_in[8];
  const float* bias     = (const float*)d_in[9];
  const float* lng      = (const float*)d_in[10];
  const float* lnb      = (const float*)d_in[11];
  const int*   eidx     = (const int*)d_in[12];
  const int*   batch    = (const int*)d_in[13];
  const int*   srcp = eidx;
  const int*   dstp = eidx + N_EDG;

  char* ws = (char*)d_ws;
  size_t off = 0;
  auto alloc = [&](size_t bytes)->char*{
    size_t o = off;
    off = (off + bytes + 511) & ~(size_t)511;
    return ws + o;
  };
  int*   cursor   = (int*)  alloc((size_t)N_NODES * 4);
  int*   bnd      = (int*)  alloc((size_t)(NB + 1) * 4);
  float* s_src    = (float*)alloc((size_t)N_NODES * 4 * 4);
  float* s_dst    = (float*)alloc((size_t)N_NODES * 4 * 4);
  float* vfold    = (float*)alloc((size_t)3 * 1152 * 4);
  u32*   erec     = (u32*)  alloc((size_t)N_NODES * PAD * 32);
  u32*   agg      = (u32*)  alloc((size_t)N_NODES * 256 * 4);   // up to [N,512] bf16
  u16*   xbf0     = (u16*)  alloc((size_t)N_NODES * EMBD * 2);
  u16*   xbfA     = (u16*)  alloc((size_t)N_NODES * HIDD * 2);
  u16*   xbfB     = (u16*)  alloc((size_t)N_NODES * HIDD * 2);
  u16*   wstk0    = (u16*)  alloc((size_t)128 * 128 * 2);
  u16*   wstk1    = (u16*)  alloc((size_t)128 * 512 * 2);
  u16*   wstk2    = (u16*)  alloc((size_t)128 * 512 * 2);

  hipMemsetAsync(cursor, 0, (size_t)N_NODES * 4, stream);
  k_setup<<<3170, 256, 0, stream>>>(lin_w[0], lin_w[1], lin_w[2], lin_edge,
                                    att_src, att_dst, att_edge, x, batch,
                                    vfold, wstk0, wstk1, wstk2, xbf0, bnd);
  k_edgescatter<<<1329, 256, 0, stream>>>(ea, srcp, dstp, cursor, vfold, erec,
                                          x, (float4*)s_src, (float4*)s_dst);

  int aggrGrid = (N_NODES + 3) / 4;
  int gemmGrid = (N_NODES + 63) / 64;

  // ---- layer 0 ----
  k_aggr<EMBD><<<aggrGrid, 256, 0, stream>>>((const u32*)xbf0, erec,
      (const float4*)s_src, (const float4*)s_dst, cursor, 0, agg);
  k_gemmLN<128, 1><<<gemmGrid, 256, 0, stream>>>((const u16*)agg, wstk0,
      bias + 0 * HIDD, lng + 0 * HIDD, lnb + 0 * HIDD, vfold + 1 * 1152,
      xbfA, (float4*)s_src, (float4*)s_dst, N_NODES);

  // ---- layer 1 ----
  k_aggr<HIDD><<<aggrGrid, 256, 0, stream>>>((const u32*)xbfA, erec,
      (const float4*)s_src, (const float4*)s_dst, cursor, 1, agg);
  k_gemmLN<512, 1><<<gemmGrid, 256, 0, stream>>>((const u16*)agg, wstk1,
      bias + 1 * HIDD, lng + 1 * HIDD, lnb + 1 * HIDD, vfold + 2 * 1152,
      xbfB, (float4*)s_src, (float4*)s_dst, N_NODES);

  // ---- layer 2 ----
  k_aggr<HIDD><<<aggrGrid, 256, 0, stream>>>((const u32*)xbfB, erec,
      (const float4*)s_src, (const float4*)s_dst, cursor, 2, agg);
  k_gemmLN<512, 0><<<gemmGrid, 256, 0, stream>>>((const u16*)agg, wstk2,
      bias + 2 * HIDD, lng + 2 * HIDD, lnb + 2 * HIDD, vfold,
      xbfA, (float4*)s_src, (float4*)s_dst, N_NODES);

  k_pool<<<NB, 256, 0, stream>>>(xbfA, bnd, (float*)d_out);
}

// Round 18
// 187.574 us; speedup vs baseline: 1.7976x; 1.1910x over previous
//
#include <hip/hip_runtime.h>
#include <math.h>

#define N_NODES 20000
#define N_EDG   320000
#define NB      64
#define EMBD    32
#define HIDD    128
#define NHEAD   4
#define OUTC    512      // H * HID
#define LN_EPS  1e-5f
#define NEG_SLOPE 0.2f
#define PAD     64       // padded-CSR slots per node (max deg ~40 for this dataset)

typedef unsigned int u32;
typedef unsigned short u16;
typedef __attribute__((ext_vector_type(8))) short s16x8;
typedef __attribute__((ext_vector_type(4))) float f32x4;

__device__ __forceinline__ float lrelu(float x){ return x >= 0.f ? x : NEG_SLOPE * x; }

__device__ __forceinline__ float2 bf2f(u32 p){
  float2 r;
  r.x = __uint_as_float(p << 16);
  r.y = __uint_as_float(p & 0xffff0000u);
  return r;
}
__device__ __forceinline__ float bf1f(u16 v){ return __uint_as_float(((u32)v) << 16); }
__device__ __forceinline__ u16 f2bf(float a){
  u32 ua = __float_as_uint(a);
  return (u16)((ua + 0x7fffu + ((ua >> 16) & 1u)) >> 16);
}
__device__ __forceinline__ u32 pack2bf(float a, float b){
  return (u32)f2bf(a) | ((u32)f2bf(b) << 16);
}

__device__ __forceinline__ float wsum(float v){
  #pragma unroll
  for (int off = 32; off > 0; off >>= 1) v += __shfl_xor(v, off);
  return v;
}
__device__ __forceinline__ float wmax(float v){
  #pragma unroll
  for (int off = 32; off > 0; off >>= 1) v = fmaxf(v, __shfl_xor(v, off));
  return v;
}

// ---------------- fused setup: fold + stacked-W cvt + cvt_x + bounds ----------------
// blocks [0,15): fold; [15,591): wstk cvt; [591,3091): cvt_x; [3091,3170): bounds
// wstk layouts (bf16, out-ch major): wstk0 [128][128] f=h*32+k; wstk1/2 [128][512] f=h*128+k
__global__ __launch_bounds__(256) void k_setup(const float* __restrict__ W0,
                                               const float* __restrict__ W1,
                                               const float* __restrict__ W2,
                                               const float* __restrict__ lin_edge,
                                               const float* __restrict__ att_src,
                                               const float* __restrict__ att_dst,
                                               const float* __restrict__ att_edge,
                                               const float* __restrict__ x,
                                               const int* __restrict__ batch,
                                               float* __restrict__ vfold,
                                               u16* __restrict__ wstk0, u16* __restrict__ wstk1,
                                               u16* __restrict__ wstk2, u16* __restrict__ xb,
                                               int* __restrict__ bnd){
  int b = blockIdx.x;
  if (b < 15){
    int L = b / 5;
    int in_dim = L ? HIDD : EMBD;
    const float* W  = (L == 0) ? W0 : ((L == 1) ? W1 : W2);
    const float* We = lin_edge + (size_t)L * EMBD * OUTC;
    const float* as = att_src + L * 512;
    const float* ad = att_dst + L * 512;
    const float* ae = att_edge + L * 512;
    float* vf = vfold + L * 1152;
    int j = (b % 5) * 256 + threadIdx.x;
    int nsrc = in_dim * NHEAD;
    if (j < nsrc){
      int k = j >> 2, h = j & 3;
      float s = 0.f;
      for (int c = 0; c < HIDD; ++c) s += W[k * OUTC + h * HIDD + c] * as[h * HIDD + c];
      vf[k * 4 + h] = s;
    } else if (j < 2 * nsrc){
      int jj = j - nsrc; int k = jj >> 2, h = jj & 3;
      float s = 0.f;
      for (int c = 0; c < HIDD; ++c) s += W[k * OUTC + h * HIDD + c] * ad[h * HIDD + c];
      vf[512 + k * 4 + h] = s;
    } else if (j < 2 * nsrc + EMBD * NHEAD){
      int jj = j - 2 * nsrc; int k = jj >> 2, h = jj & 3;
      float s = 0.f;
      for (int c = 0; c < HIDD; ++c) s += We[k * OUTC + h * HIDD + c] * ae[h * HIDD + c];
      vf[1024 + k * 4 + h] = s;
    }
  } else if (b < 591){
    int idx = (b - 15) * 256 + threadIdx.x;
    if (idx < 16384){
      int c = idx >> 7, f = idx & 127;
      int hh = f >> 5, k = f & 31;
      wstk0[idx] = f2bf(W0[(size_t)k * OUTC + hh * HIDD + c] * 0.25f);
    } else if (idx < 81920){
      int j = idx - 16384;
      int c = j >> 9, f = j & 511;
      int hh = f >> 7, k = f & 127;
      wstk1[j] = f2bf(W1[(size_t)k * OUTC + hh * HIDD + c] * 0.25f);
    } else if (idx < 147456){
      int j = idx - 81920;
      int c = j >> 9, f = j & 511;
      int hh = f >> 7, k = f & 127;
      wstk2[j] = f2bf(W2[(size_t)k * OUTC + hh * HIDD + c] * 0.25f);
    }
  } else if (b < 3091){
    int i = (b - 591) * 256 + threadIdx.x;
    if (i < N_NODES * EMBD) xb[i] = f2bf(x[i]);
  } else {
    int n = (b - 3091) * 256 + threadIdx.x;
    if (n >= N_NODES) return;
    int bb = batch[n];
    int bp = (n == 0) ? -1 : batch[n - 1];
    for (int g = bp + 1; g <= bb; ++g) bnd[g] = n;
    if (n == N_NODES - 1){
      for (int g = bb + 1; g <= NB; ++g) bnd[g] = N_NODES;
    }
  }
}

// ---------------- padded-CSR scatter + edge projection + layer-0 nodelin ----------------
// blocks [0,1250): edges; [1250,1329): layer-0 s_src/s_dst from f32 x
__global__ __launch_bounds__(256) void k_edgescatter(const float* __restrict__ ea,
                                                     const int* __restrict__ src,
                                                     const int* __restrict__ dst,
                                                     int* __restrict__ cursor,
                                                     const float* __restrict__ vfold,
                                                     u32* __restrict__ erec,
                                                     const float* __restrict__ x,
                                                     float4* __restrict__ s_src,
                                                     float4* __restrict__ s_dst){
  __shared__ float vsh[1024];
  int b = blockIdx.x;
  if (b < 1250){
    for (int i = threadIdx.x; i < 384; i += 256)
      vsh[i] = vfold[(i >> 7) * 1152 + 1024 + (i & 127)];
    __syncthreads();
    int e = b * 256 + threadIdx.x;
    if (e >= N_EDG) return;
    int d = dst[e];
    int p = atomicAdd(&cursor[d], 1);
    if (p >= PAD) return;
    float4 a[8];
    const float4* er = (const float4*)(ea + (size_t)e * EMBD);
    #pragma unroll
    for (int i = 0; i < 8; ++i) a[i] = er[i];
    u32 packed[6];
    #pragma unroll
    for (int L = 0; L < 3; ++L){
      const float* v = vsh + L * 128;
      float ev[4] = {0,0,0,0};
      #pragma unroll
      for (int q = 0; q < 8; ++q){
        #pragma unroll
        for (int h = 0; h < 4; ++h){
          ev[h] += a[q].x * v[(q*4+0)*4+h] + a[q].y * v[(q*4+1)*4+h]
                 + a[q].z * v[(q*4+2)*4+h] + a[q].w * v[(q*4+3)*4+h];
        }
      }
      packed[L*2+0] = pack2bf(ev[0], ev[1]);
      packed[L*2+1] = pack2bf(ev[2], ev[3]);
    }
    u32* rp = erec + ((size_t)d * PAD + p) * 8;
    *(uint4*)rp       = make_uint4(packed[0], packed[1], packed[2], packed[3]);
    *(uint4*)(rp + 4) = make_uint4(packed[4], packed[5], (u32)src[e], 0u);
  } else {
    for (int i = threadIdx.x; i < 1024; i += 256) vsh[i] = vfold[i];
    __syncthreads();
    int n = (b - 1250) * 256 + threadIdx.x;
    if (n >= N_NODES) return;
    float a[4] = {0,0,0,0}, d[4] = {0,0,0,0};
    const float* xr = x + (size_t)n * EMBD;
    #pragma unroll
    for (int k4 = 0; k4 < EMBD; k4 += 4){
      float4 xv = *(const float4*)(xr + k4);
      #pragma unroll
      for (int h = 0; h < 4; ++h){
        a[h] += xv.x * vsh[(k4+0)*4+h] + xv.y * vsh[(k4+1)*4+h]
              + xv.z * vsh[(k4+2)*4+h] + xv.w * vsh[(k4+3)*4+h];
        d[h] += xv.x * vsh[512+(k4+0)*4+h] + xv.y * vsh[512+(k4+1)*4+h]
              + xv.z * vsh[512+(k4+2)*4+h] + xv.w * vsh[512+(k4+3)*4+h];
      }
    }
    s_src[n] = make_float4(a[0], a[1], a[2], a[3]);
    s_dst[n] = make_float4(d[0], d[1], d[2], d[3]);
  }
}

// ---------------- x-space aggregation: agg[n][h*IN+k] = softmax-weighted sum of x rows ----------------
template<int IN>   // 32 (layer 0) or 128
__global__ __launch_bounds__(256) void k_aggr(const u32* __restrict__ Xw,   // bf16 rows, IN/2 words
                                              const u32* __restrict__ erec,
                                              const float4* __restrict__ s_src4,
                                              const float4* __restrict__ s_dst4,
                                              const int* __restrict__ cursor,
                                              int L,
                                              u32* __restrict__ agg){      // [N, 2*IN] words
  const int NW = IN / 2;     // words per x row
  const int G  = 64 / NW;    // edges processed per iteration
  __shared__ float4 wlds4[4][64];
  __shared__ int    slds[4][64];
  int wid  = threadIdx.x >> 6;
  int lane = threadIdx.x & 63;
  int n = blockIdx.x * 4 + wid;
  if (n >= N_NODES) return;
  int degn = cursor[n];
  int cnt = min(degn, PAD);

  float4 dd = s_dst4[n];
  float4 sn = s_src4[n];

  // ---- logit phase: lane-parallel, registers only ----
  float4 v = make_float4(-1e30f, -1e30f, -1e30f, -1e30f);
  float4 evv = make_float4(0.f, 0.f, 0.f, 0.f);
  int sj = 0;
  if (lane < cnt){
    const u32* rp = erec + ((size_t)n * PAD + lane) * 8;
    uint2 ep = *(const uint2*)(rp + 2 * L);
    sj = (int)rp[6];
    float2 e01 = bf2f(ep.x), e23 = bf2f(ep.y);
    evv = make_float4(e01.x, e01.y, e23.x, e23.y);
    float4 ss = s_src4[sj];
    v.x = lrelu(ss.x + dd.x + evv.x);
    v.y = lrelu(ss.y + dd.y + evv.y);
    v.z = lrelu(ss.z + dd.z + evv.z);
    v.w = lrelu(ss.w + dd.w + evv.w);
  }
  float m0 = wmax(v.x), m1 = wmax(v.y), m2 = wmax(v.z), m3 = wmax(v.w);
  float pv0 = wsum(evv.x), pv1 = wsum(evv.y), pv2 = wsum(evv.z), pv3 = wsum(evv.w);
  float invd = 1.f / fmaxf((float)degn, 1.f);
  float ll0 = lrelu(sn.x + dd.x + pv0 * invd);
  float ll1 = lrelu(sn.y + dd.y + pv1 * invd);
  float ll2 = lrelu(sn.z + dd.z + pv2 * invd);
  float ll3 = lrelu(sn.w + dd.w + pv3 * invd);
  m0 = fmaxf(m0, ll0); m1 = fmaxf(m1, ll1);
  m2 = fmaxf(m2, ll2); m3 = fmaxf(m3, ll3);
  float e0 = (lane < cnt) ? __expf(v.x - m0) : 0.f;
  float e1 = (lane < cnt) ? __expf(v.y - m1) : 0.f;
  float e2 = (lane < cnt) ? __expf(v.z - m2) : 0.f;
  float e3 = (lane < cnt) ? __expf(v.w - m3) : 0.f;
  float ws0 = __expf(ll0 - m0), ws1 = __expf(ll1 - m1);
  float ws2 = __expf(ll2 - m2), ws3 = __expf(ll3 - m3);
  float i0 = 1.f / (wsum(e0) + ws0);
  float i1 = 1.f / (wsum(e1) + ws1);
  float i2 = 1.f / (wsum(e2) + ws2);
  float i3 = 1.f / (wsum(e3) + ws3);
  if (lane < cnt){
    wlds4[wid][lane] = make_float4(e0, e1, e2, e3);
    slds[wid][lane] = sj;
  }
  asm volatile("s_waitcnt lgkmcnt(0)" ::: "memory");

  // ---- gather phase: x-space rows ----
  int wi  = lane & (NW - 1);
  int grp = lane / NW;
  float self = (grp == 0) ? 1.f : 0.f;
  float acc[8];     // [head][2ch]
  {
    float2 xx = bf2f(Xw[(size_t)n * NW + wi]);
    acc[0] = self * ws0 * xx.x; acc[1] = self * ws0 * xx.y;
    acc[2] = self * ws1 * xx.x; acc[3] = self * ws1 * xx.y;
    acc[4] = self * ws2 * xx.x; acc[5] = self * ws2 * xx.y;
    acc[6] = self * ws3 * xx.x; acc[7] = self * ws3 * xx.y;
  }
  const float* wbase = (const float*)&wlds4[wid][0];
  #pragma unroll 4
  for (int jj = 0; jj < cnt; jj += G){
    int j = jj + grp;
    if (j < cnt){
      float w0 = wbase[j * 4 + 0];
      float w1 = wbase[j * 4 + 1];
      float w2 = wbase[j * 4 + 2];
      float w3 = wbase[j * 4 + 3];
      int  sv = slds[wid][j];
      float2 xx = bf2f(Xw[(size_t)sv * NW + wi]);
      acc[0] = fmaf(w0, xx.x, acc[0]); acc[1] = fmaf(w0, xx.y, acc[1]);
      acc[2] = fmaf(w1, xx.x, acc[2]); acc[3] = fmaf(w1, xx.y, acc[3]);
      acc[4] = fmaf(w2, xx.x, acc[4]); acc[5] = fmaf(w2, xx.y, acc[5]);
      acc[6] = fmaf(w3, xx.x, acc[6]); acc[7] = fmaf(w3, xx.y, acc[7]);
    }
  }
  asm volatile("s_waitcnt lgkmcnt(0)" ::: "memory");
  if (G > 1){
    #pragma unroll
    for (int q = 0; q < 8; ++q){
      acc[q] += __shfl_xor(acc[q], 16);
      acc[q] += __shfl_xor(acc[q], 32);
    }
  }
  if (grp == 0){
    u32* ar = agg + (size_t)n * (2 * IN);
    ar[0 * NW + wi] = pack2bf(acc[0] * i0, acc[1] * i0);
    ar[1 * NW + wi] = pack2bf(acc[2] * i1, acc[3] * i1);
    ar[2 * NW + wi] = pack2bf(acc[4] * i2, acc[5] * i2);
    ar[3 * NW + wi] = pack2bf(acc[6] * i3, acc[7] * i3);
  }
}

// ---------------- stacked-head GEMM + bias + LN + ReLU + next-layer logits ----------------
// C[n][c] = sum_f agg[n][f] * Wstk[c][f]  (Wstk pre-scaled by 1/4)
template<int KF, int NEXT>   // KF = 128 or 512
__global__ __launch_bounds__(256) void k_gemmLN(const u16* __restrict__ Ab,   // agg [N,KF] bf16
                                                const u16* __restrict__ Bt,   // [128][KF] bf16
                                                const float* __restrict__ bias,
                                                const float* __restrict__ lng,
                                                const float* __restrict__ lnb,
                                                const float* __restrict__ vfN, // next vfold (1024 f) or junk
                                                u16* __restrict__ Xout,       // [N,128] bf16
                                                float4* __restrict__ s_srcN,
                                                float4* __restrict__ s_dstN,
                                                int M){
  const int CH = 136;   // BK=128 + 8 pad
  __shared__ u16 ldsA[64 * CH];
  __shared__ u16 ldsB[128 * CH];
  __shared__ float prm[384 + 1024];
  int bm = blockIdx.x * 64;
  int t = threadIdx.x;
  for (int i = t; i < 384; i += 256){
    const float* sp = (i < 128) ? bias : ((i < 256) ? lng : lnb);
    prm[i] = sp[i & 127];
  }
  if (NEXT){
    for (int i = t; i < 1024; i += 256) prm[384 + i] = vfN[i];
  }
  int w = t >> 6, lane = t & 63, r = lane & 15, g = lane >> 4;
  f32x4 acc[8];
  #pragma unroll
  for (int i = 0; i < 8; ++i) acc[i] = (f32x4){0.f, 0.f, 0.f, 0.f};

  for (int kt = 0; kt < KF; kt += 128){
    for (int f = t; f < 64 * 16; f += 256){
      int row = f >> 4, c8 = f & 15;
      int gm = bm + row;
      uint4 vv = make_uint4(0, 0, 0, 0);
      if (gm < M) vv = *(const uint4*)(Ab + (size_t)gm * KF + kt + c8 * 8);
      *(uint4*)&ldsA[row * CH + c8 * 8] = vv;
    }
    for (int f = t; f < 128 * 16; f += 256){
      int row = f >> 4, c8 = f & 15;
      *(uint4*)&ldsB[row * CH + c8 * 8] = *(const uint4*)(Bt + (size_t)row * KF + kt + c8 * 8);
    }
    __syncthreads();
    #pragma unroll
    for (int k0 = 0; k0 < 128; k0 += 32){
      s16x8 a = *(const s16x8*)(&ldsA[(w * 16 + r) * CH + k0 + g * 8]);
      #pragma unroll
      for (int nf = 0; nf < 8; ++nf){
        s16x8 b = *(const s16x8*)(&ldsB[(nf * 16 + r) * CH + k0 + g * 8]);
        acc[nf] = __builtin_amdgcn_mfma_f32_16x16x32_bf16(a, b, acc[nf], 0, 0, 0);
      }
    }
    __syncthreads();
  }

  // epilogue: row gm = bm + w*16 + g*4 + i; channel = nf*16 + r (16 r-lanes per row)
  #pragma unroll
  for (int i = 0; i < 4; ++i){
    int gm = bm + w * 16 + g * 4 + i;
    float tt[8];
    float rs = 0.f;
    #pragma unroll
    for (int nf = 0; nf < 8; ++nf){
      tt[nf] = acc[nf][i] + prm[nf * 16 + r];
      rs += tt[nf];
    }
    rs += __shfl_xor(rs, 1); rs += __shfl_xor(rs, 2);
    rs += __shfl_xor(rs, 4); rs += __shfl_xor(rs, 8);
    float mu = rs * (1.f / 128.f);
    float sq = 0.f;
    #pragma unroll
    for (int nf = 0; nf < 8; ++nf){ tt[nf] -= mu; sq += tt[nf] * tt[nf]; }
    sq += __shfl_xor(sq, 1); sq += __shfl_xor(sq, 2);
    sq += __shfl_xor(sq, 4); sq += __shfl_xor(sq, 8);
    float invs = rsqrtf(sq * (1.f / 128.f) + LN_EPS);
    float pa0 = 0.f, pa1 = 0.f, pa2 = 0.f, pa3 = 0.f;
    float pd0 = 0.f, pd1 = 0.f, pd2 = 0.f, pd3 = 0.f;
    #pragma unroll
    for (int nf = 0; nf < 8; ++nf){
      int ch = nf * 16 + r;
      float o = fmaxf(tt[nf] * invs * prm[128 + ch] + prm[256 + ch], 0.f);
      if (gm < M) Xout[(size_t)gm * HIDD + ch] = f2bf(o);
      if (NEXT){
        pa0 = fmaf(o, prm[384 + ch * 4 + 0], pa0);
        pa1 = fmaf(o, prm[384 + ch * 4 + 1], pa1);
        pa2 = fmaf(o, prm[384 + ch * 4 + 2], pa2);
        pa3 = fmaf(o, prm[384 + ch * 4 + 3], pa3);
        pd0 = fmaf(o, prm[384 + 512 + ch * 4 + 0], pd0);
        pd1 = fmaf(o, prm[384 + 512 + ch * 4 + 1], pd1);
        pd2 = fmaf(o, prm[384 + 512 + ch * 4 + 2], pd2);
        pd3 = fmaf(o, prm[384 + 512 + ch * 4 + 3], pd3);
      }
    }
    if (NEXT){
      #pragma unroll
      for (int m = 1; m < 16; m <<= 1){
        pa0 += __shfl_xor(pa0, m); pa1 += __shfl_xor(pa1, m);
        pa2 += __shfl_xor(pa2, m); pa3 += __shfl_xor(pa3, m);
        pd0 += __shfl_xor(pd0, m); pd1 += __shfl_xor(pd1, m);
        pd2 += __shfl_xor(pd2, m); pd3 += __shfl_xor(pd3, m);
      }
      if (r == 0 && gm < M){
        s_srcN[gm] = make_float4(pa0, pa1, pa2, pa3);
        s_dstN[gm] = make_float4(pd0, pd1, pd2, pd3);
      }
    }
  }
}

// ---------------- global mean pool: vectorized cooperative reads ----------------
__global__ __launch_bounds__(256) void k_pool(const u32* __restrict__ Xw,   // bf16 words [N,64]
                                              const int* __restrict__ bnd,
                                              float* __restrict__ out){
  __shared__ float red[16][128];
  int g = blockIdx.x;
  int s = bnd[g], e = bnd[g + 1];
  int rg = threadIdx.x >> 4;      // 0..15 row group
  int cg = threadIdx.x & 15;      // 0..15 channel group (8 channels each)
  float acc[8] = {0,0,0,0,0,0,0,0};
  for (int n = s + rg; n < e; n += 16){
    uint4 v = *(const uint4*)(Xw + (size_t)n * 64 + cg * 4);
    float2 p0 = bf2f(v.x), p1 = bf2f(v.y), p2 = bf2f(v.z), p3 = bf2f(v.w);
    acc[0] += p0.x; acc[1] += p0.y; acc[2] += p1.x; acc[3] += p1.y;
    acc[4] += p2.x; acc[5] += p2.y; acc[6] += p3.x; acc[7] += p3.y;
  }
  #pragma unroll
  for (int i = 0; i < 8; ++i) red[rg][cg * 8 + i] = acc[i];
  __syncthreads();
  int c = threadIdx.x;
  if (c < 128){
    float sthis = 0.f;
    #pragma unroll
    for (int r = 0; r < 16; ++r) sthis += red[r][c];
    out[g * HIDD + c] = sthis / fmaxf((float)(e - s), 1.f);
  }
}

extern "C" void kernel_launch(void* const* d_in, const int* in_sizes, int n_in,
                              void* d_out, int out_size, void* d_ws, size_t ws_size,
                              hipStream_t stream){
  const float* x        = (const float*)d_in[0];
  const float* ea       = (const float*)d_in[1];
  const float* lin_w[3] = {(const float*)d_in[2], (const float*)d_in[3], (const float*)d_in[4]};
  const float* lin_edge = (const float*)d_in[5];
  const float* att_src  = (const float*)d_in[6];
  const float* att_dst  = (const float*)d_in[7];
  const float* att_edge = (const float*)d_in[8];
  const float* bias     = (const float*)d_in[9];
  const float* lng      = (const float*)d_in[10];
  const float* lnb      = (const float*)d_in[11];
  const int*   eidx     = (const int*)d_in[12];
  const int*   batch    = (const int*)d_in[13];
  const int*   srcp = eidx;
  const int*   dstp = eidx + N_EDG;

  char* ws = (char*)d_ws;
  size_t off = 0;
  auto alloc = [&](size_t bytes)->char*{
    size_t o = off;
    off = (off + bytes + 511) & ~(size_t)511;
    return ws + o;
  };
  int*   cursor   = (int*)  alloc((size_t)N_NODES * 4);
  int*   bnd      = (int*)  alloc((size_t)(NB + 1) * 4);
  float* s_src    = (float*)alloc((size_t)N_NODES * 4 * 4);
  float* s_dst    = (float*)alloc((size_t)N_NODES * 4 * 4);
  float* vfold    = (float*)alloc((size_t)3 * 1152 * 4);
  u32*   erec     = (u32*)  alloc((size_t)N_NODES * PAD * 32);
  u32*   agg      = (u32*)  alloc((size_t)N_NODES * 256 * 4);   // up to [N,512] bf16
  u16*   xbf0     = (u16*)  alloc((size_t)N_NODES * EMBD * 2);
  u16*   xbfA     = (u16*)  alloc((size_t)N_NODES * HIDD * 2);
  u16*   xbfB     = (u16*)  alloc((size_t)N_NODES * HIDD * 2);
  u16*   wstk0    = (u16*)  alloc((size_t)128 * 128 * 2);
  u16*   wstk1    = (u16*)  alloc((size_t)128 * 512 * 2);
  u16*   wstk2    = (u16*)  alloc((size_t)128 * 512 * 2);

  hipMemsetAsync(cursor, 0, (size_t)N_NODES * 4, stream);
  k_setup<<<3170, 256, 0, stream>>>(lin_w[0], lin_w[1], lin_w[2], lin_edge,
                                    att_src, att_dst, att_edge, x, batch,
                                    vfold, wstk0, wstk1, wstk2, xbf0, bnd);
  k_edgescatter<<<1329, 256, 0, stream>>>(ea, srcp, dstp, cursor, vfold, erec,
                                          x, (float4*)s_src, (float4*)s_dst);

  int aggrGrid = (N_NODES + 3) / 4;
  int gemmGrid = (N_NODES + 63) / 64;

  // ---- layer 0 ----
  k_aggr<EMBD><<<aggrGrid, 256, 0, stream>>>((const u32*)xbf0, erec,
      (const float4*)s_src, (const float4*)s_dst, cursor, 0, agg);
  k_gemmLN<128, 1><<<gemmGrid, 256, 0, stream>>>((const u16*)agg, wstk0,
      bias + 0 * HIDD, lng + 0 * HIDD, lnb + 0 * HIDD, vfold + 1 * 1152,
      xbfA, (float4*)s_src, (float4*)s_dst, N_NODES);

  // ---- layer 1 ----
  k_aggr<HIDD><<<aggrGrid, 256, 0, stream>>>((const u32*)xbfA, erec,
      (const float4*)s_src, (const float4*)s_dst, cursor, 1, agg);
  k_gemmLN<512, 1><<<gemmGrid, 256, 0, stream>>>((const u16*)agg, wstk1,
      bias + 1 * HIDD, lng + 1 * HIDD, lnb + 1 * HIDD, vfold + 2 * 1152,
      xbfB, (float4*)s_src, (float4*)s_dst, N_NODES);

  // ---- layer 2 ----
  k_aggr<HIDD><<<aggrGrid, 256, 0, stream>>>((const u32*)xbfB, erec,
      (const float4*)s_src, (const float4*)s_dst, cursor, 2, agg);
  k_gemmLN<512, 0><<<gemmGrid, 256, 0, stream>>>((const u16*)agg, wstk2,
      bias + 2 * HIDD, lng + 2 * HIDD, lnb + 2 * HIDD, vfold,
      xbfA, (float4*)s_src, (float4*)s_dst, N_NODES);

  k_pool<<<NB, 256, 0, stream>>>((const u32*)xbfA, bnd, (float*)d_out);
}

// Round 19
// 182.387 us; speedup vs baseline: 1.8487x; 1.0284x over previous
//
#include <hip/hip_runtime.h>
#include <math.h>

#define N_NODES 20000
#define N_EDG   320000
#define NB      64
#define EMBD    32
#define HIDD    128
#define NHEAD   4
#define OUTC    512      // H * HID
#define LN_EPS  1e-5f
#define NEG_SLOPE 0.2f
#define PAD     64       // padded-CSR slots per node (max deg ~40 for this dataset)

typedef unsigned int u32;
typedef unsigned short u16;
typedef __attribute__((ext_vector_type(8))) short s16x8;
typedef __attribute__((ext_vector_type(4))) float f32x4;

__device__ __forceinline__ float lrelu(float x){ return x >= 0.f ? x : NEG_SLOPE * x; }

__device__ __forceinline__ float2 bf2f(u32 p){
  float2 r;
  r.x = __uint_as_float(p << 16);
  r.y = __uint_as_float(p & 0xffff0000u);
  return r;
}
__device__ __forceinline__ float bf1f(u16 v){ return __uint_as_float(((u32)v) << 16); }
__device__ __forceinline__ u16 f2bf(float a){
  u32 ua = __float_as_uint(a);
  return (u16)((ua + 0x7fffu + ((ua >> 16) & 1u)) >> 16);
}
__device__ __forceinline__ u32 pack2bf(float a, float b){
  return (u32)f2bf(a) | ((u32)f2bf(b) << 16);
}

__device__ __forceinline__ float wsum(float v){
  #pragma unroll
  for (int off = 32; off > 0; off >>= 1) v += __shfl_xor(v, off);
  return v;
}
__device__ __forceinline__ float wmax(float v){
  #pragma unroll
  for (int off = 32; off > 0; off >>= 1) v = fmaxf(v, __shfl_xor(v, off));
  return v;
}

// ---------------- fused setup: fold + stacked-W cvt + cvt_x + bounds + cursor-zero ----------------
// blocks [0,15): fold; [15,591): wstk cvt; [591,3091): cvt_x; [3091,3170): bounds; [3170,3249): cursor=0
__global__ __launch_bounds__(256) void k_setup(const float* __restrict__ W0,
                                               const float* __restrict__ W1,
                                               const float* __restrict__ W2,
                                               const float* __restrict__ lin_edge,
                                               const float* __restrict__ att_src,
                                               const float* __restrict__ att_dst,
                                               const float* __restrict__ att_edge,
                                               const float* __restrict__ x,
                                               const int* __restrict__ batch,
                                               float* __restrict__ vfold,
                                               u16* __restrict__ wstk0, u16* __restrict__ wstk1,
                                               u16* __restrict__ wstk2, u16* __restrict__ xb,
                                               int* __restrict__ bnd,
                                               int* __restrict__ cursor){
  int b = blockIdx.x;
  if (b < 15){
    int L = b / 5;
    int in_dim = L ? HIDD : EMBD;
    const float* W  = (L == 0) ? W0 : ((L == 1) ? W1 : W2);
    const float* We = lin_edge + (size_t)L * EMBD * OUTC;
    const float* as = att_src + L * 512;
    const float* ad = att_dst + L * 512;
    const float* ae = att_edge + L * 512;
    float* vf = vfold + L * 1152;
    int j = (b % 5) * 256 + threadIdx.x;
    int nsrc = in_dim * NHEAD;
    if (j < nsrc){
      int k = j >> 2, h = j & 3;
      float s = 0.f;
      for (int c = 0; c < HIDD; ++c) s += W[k * OUTC + h * HIDD + c] * as[h * HIDD + c];
      vf[k * 4 + h] = s;
    } else if (j < 2 * nsrc){
      int jj = j - nsrc; int k = jj >> 2, h = jj & 3;
      float s = 0.f;
      for (int c = 0; c < HIDD; ++c) s += W[k * OUTC + h * HIDD + c] * ad[h * HIDD + c];
      vf[512 + k * 4 + h] = s;
    } else if (j < 2 * nsrc + EMBD * NHEAD){
      int jj = j - 2 * nsrc; int k = jj >> 2, h = jj & 3;
      float s = 0.f;
      for (int c = 0; c < HIDD; ++c) s += We[k * OUTC + h * HIDD + c] * ae[h * HIDD + c];
      vf[1024 + k * 4 + h] = s;
    }
  } else if (b < 591){
    int idx = (b - 15) * 256 + threadIdx.x;
    if (idx < 16384){
      int c = idx >> 7, f = idx & 127;
      int hh = f >> 5, k = f & 31;
      wstk0[idx] = f2bf(W0[(size_t)k * OUTC + hh * HIDD + c] * 0.25f);
    } else if (idx < 81920){
      int j = idx - 16384;
      int c = j >> 9, f = j & 511;
      int hh = f >> 7, k = f & 127;
      wstk1[j] = f2bf(W1[(size_t)k * OUTC + hh * HIDD + c] * 0.25f);
    } else if (idx < 147456){
      int j = idx - 81920;
      int c = j >> 9, f = j & 511;
      int hh = f >> 7, k = f & 127;
      wstk2[j] = f2bf(W2[(size_t)k * OUTC + hh * HIDD + c] * 0.25f);
    }
  } else if (b < 3091){
    int i = (b - 591) * 256 + threadIdx.x;
    if (i < N_NODES * EMBD) xb[i] = f2bf(x[i]);
  } else if (b < 3170){
    int n = (b - 3091) * 256 + threadIdx.x;
    if (n >= N_NODES) return;
    int bb = batch[n];
    int bp = (n == 0) ? -1 : batch[n - 1];
    for (int g = bp + 1; g <= bb; ++g) bnd[g] = n;
    if (n == N_NODES - 1){
      for (int g = bb + 1; g <= NB; ++g) bnd[g] = N_NODES;
    }
  } else {
    int n = (b - 3170) * 256 + threadIdx.x;
    if (n < N_NODES) cursor[n] = 0;
  }
}

// ---------------- padded-CSR scatter + edge projection + layer-0 nodelin ----------------
// blocks [0,1250): edges; [1250,1329): layer-0 s_src/s_dst from f32 x
__global__ __launch_bounds__(256) void k_edgescatter(const float* __restrict__ ea,
                                                     const int* __restrict__ src,
                                                     const int* __restrict__ dst,
                                                     int* __restrict__ cursor,
                                                     const float* __restrict__ vfold,
                                                     u32* __restrict__ erec,
                                                     const float* __restrict__ x,
                                                     float4* __restrict__ s_src,
                                                     float4* __restrict__ s_dst){
  __shared__ float vsh[1024];
  int b = blockIdx.x;
  if (b < 1250){
    for (int i = threadIdx.x; i < 384; i += 256)
      vsh[i] = vfold[(i >> 7) * 1152 + 1024 + (i & 127)];
    __syncthreads();
    int e = b * 256 + threadIdx.x;
    if (e >= N_EDG) return;
    int d = dst[e];
    int p = atomicAdd(&cursor[d], 1);
    if (p >= PAD) return;
    // low-VGPR projection: one float4 of ea live at a time, 12 accumulators
    float ev0[4] = {0,0,0,0}, ev1[4] = {0,0,0,0}, ev2[4] = {0,0,0,0};
    const float4* er = (const float4*)(ea + (size_t)e * EMBD);
    #pragma unroll
    for (int q = 0; q < 8; ++q){
      float4 aq = er[q];
      #pragma unroll
      for (int h = 0; h < 4; ++h){
        ev0[h] += aq.x * vsh[(q*4+0)*4+h] + aq.y * vsh[(q*4+1)*4+h]
                + aq.z * vsh[(q*4+2)*4+h] + aq.w * vsh[(q*4+3)*4+h];
        ev1[h] += aq.x * vsh[128+(q*4+0)*4+h] + aq.y * vsh[128+(q*4+1)*4+h]
                + aq.z * vsh[128+(q*4+2)*4+h] + aq.w * vsh[128+(q*4+3)*4+h];
        ev2[h] += aq.x * vsh[256+(q*4+0)*4+h] + aq.y * vsh[256+(q*4+1)*4+h]
                + aq.z * vsh[256+(q*4+2)*4+h] + aq.w * vsh[256+(q*4+3)*4+h];
      }
    }
    u32* rp = erec + ((size_t)d * PAD + p) * 8;
    *(uint4*)rp       = make_uint4(pack2bf(ev0[0], ev0[1]), pack2bf(ev0[2], ev0[3]),
                                   pack2bf(ev1[0], ev1[1]), pack2bf(ev1[2], ev1[3]));
    *(uint4*)(rp + 4) = make_uint4(pack2bf(ev2[0], ev2[1]), pack2bf(ev2[2], ev2[3]),
                                   (u32)src[e], 0u);
  } else {
    for (int i = threadIdx.x; i < 1024; i += 256) vsh[i] = vfold[i];
    __syncthreads();
    int n = (b - 1250) * 256 + threadIdx.x;
    if (n >= N_NODES) return;
    float a[4] = {0,0,0,0}, d[4] = {0,0,0,0};
    const float* xr = x + (size_t)n * EMBD;
    #pragma unroll
    for (int k4 = 0; k4 < EMBD; k4 += 4){
      float4 xv = *(const float4*)(xr + k4);
      #pragma unroll
      for (int h = 0; h < 4; ++h){
        a[h] += xv.x * vsh[(k4+0)*4+h] + xv.y * vsh[(k4+1)*4+h]
              + xv.z * vsh[(k4+2)*4+h] + xv.w * vsh[(k4+3)*4+h];
        d[h] += xv.x * vsh[512+(k4+0)*4+h] + xv.y * vsh[512+(k4+1)*4+h]
              + xv.z * vsh[512+(k4+2)*4+h] + xv.w * vsh[512+(k4+3)*4+h];
      }
    }
    s_src[n] = make_float4(a[0], a[1], a[2], a[3]);
    s_dst[n] = make_float4(d[0], d[1], d[2], d[3]);
  }
}

// ---------------- x-space aggregation: agg[n][h*IN+k] = softmax-weighted sum of x rows ----------------
template<int IN>   // 32 (layer 0) or 128
__global__ __launch_bounds__(256) void k_aggr(const u32* __restrict__ Xw,   // bf16 rows, IN/2 words
                                              const u32* __restrict__ erec,
                                              const float4* __restrict__ s_src4,
                                              const float4* __restrict__ s_dst4,
                                              const int* __restrict__ cursor,
                                              int L,
                                              u32* __restrict__ agg){      // [N, 2*IN] words
  const int NW = IN / 2;     // words per x row
  const int G  = 64 / NW;    // edges processed per iteration
  __shared__ float4 wlds4[4][64];
  __shared__ int    slds[4][64];
  int wid  = threadIdx.x >> 6;
  int lane = threadIdx.x & 63;
  int n = blockIdx.x * 4 + wid;
  if (n >= N_NODES) return;
  int degn = cursor[n];
  int cnt = min(degn, PAD);

  float4 dd = s_dst4[n];
  float4 sn = s_src4[n];

  // ---- logit phase: lane-parallel, registers only ----
  float4 v = make_float4(-1e30f, -1e30f, -1e30f, -1e30f);
  float4 evv = make_float4(0.f, 0.f, 0.f, 0.f);
  int sj = 0;
  if (lane < cnt){
    const u32* rp = erec + ((size_t)n * PAD + lane) * 8;
    uint2 ep = *(const uint2*)(rp + 2 * L);
    sj = (int)rp[6];
    float2 e01 = bf2f(ep.x), e23 = bf2f(ep.y);
    evv = make_float4(e01.x, e01.y, e23.x, e23.y);
    float4 ss = s_src4[sj];
    v.x = lrelu(ss.x + dd.x + evv.x);
    v.y = lrelu(ss.y + dd.y + evv.y);
    v.z = lrelu(ss.z + dd.z + evv.z);
    v.w = lrelu(ss.w + dd.w + evv.w);
  }
  float m0 = wmax(v.x), m1 = wmax(v.y), m2 = wmax(v.z), m3 = wmax(v.w);
  float pv0 = wsum(evv.x), pv1 = wsum(evv.y), pv2 = wsum(evv.z), pv3 = wsum(evv.w);
  float invd = 1.f / fmaxf((float)degn, 1.f);
  float ll0 = lrelu(sn.x + dd.x + pv0 * invd);
  float ll1 = lrelu(sn.y + dd.y + pv1 * invd);
  float ll2 = lrelu(sn.z + dd.z + pv2 * invd);
  float ll3 = lrelu(sn.w + dd.w + pv3 * invd);
  m0 = fmaxf(m0, ll0); m1 = fmaxf(m1, ll1);
  m2 = fmaxf(m2, ll2); m3 = fmaxf(m3, ll3);
  float e0 = (lane < cnt) ? __expf(v.x - m0) : 0.f;
  float e1 = (lane < cnt) ? __expf(v.y - m1) : 0.f;
  float e2 = (lane < cnt) ? __expf(v.z - m2) : 0.f;
  float e3 = (lane < cnt) ? __expf(v.w - m3) : 0.f;
  float ws0 = __expf(ll0 - m0), ws1 = __expf(ll1 - m1);
  float ws2 = __expf(ll2 - m2), ws3 = __expf(ll3 - m3);
  float i0 = 1.f / (wsum(e0) + ws0);
  float i1 = 1.f / (wsum(e1) + ws1);
  float i2 = 1.f / (wsum(e2) + ws2);
  float i3 = 1.f / (wsum(e3) + ws3);
  if (lane < cnt){
    wlds4[wid][lane] = make_float4(e0, e1, e2, e3);
    slds[wid][lane] = sj;
  }
  asm volatile("s_waitcnt lgkmcnt(0)" ::: "memory");

  // ---- gather phase: x-space rows ----
  int wi  = lane & (NW - 1);
  int grp = lane / NW;
  float self = (grp == 0) ? 1.f : 0.f;
  float acc[8];     // [head][2ch]
  {
    float2 xx = bf2f(Xw[(size_t)n * NW + wi]);
    acc[0] = self * ws0 * xx.x; acc[1] = self * ws0 * xx.y;
    acc[2] = self * ws1 * xx.x; acc[3] = self * ws1 * xx.y;
    acc[4] = self * ws2 * xx.x; acc[5] = self * ws2 * xx.y;
    acc[6] = self * ws3 * xx.x; acc[7] = self * ws3 * xx.y;
  }
  const float* wbase = (const float*)&wlds4[wid][0];
  #pragma unroll 4
  for (int jj = 0; jj < cnt; jj += G){
    int j = jj + grp;
    if (j < cnt){
      float w0 = wbase[j * 4 + 0];
      float w1 = wbase[j * 4 + 1];
      float w2 = wbase[j * 4 + 2];
      float w3 = wbase[j * 4 + 3];
      int  sv = slds[wid][j];
      float2 xx = bf2f(Xw[(size_t)sv * NW + wi]);
      acc[0] = fmaf(w0, xx.x, acc[0]); acc[1] = fmaf(w0, xx.y, acc[1]);
      acc[2] = fmaf(w1, xx.x, acc[2]); acc[3] = fmaf(w1, xx.y, acc[3]);
      acc[4] = fmaf(w2, xx.x, acc[4]); acc[5] = fmaf(w2, xx.y, acc[5]);
      acc[6] = fmaf(w3, xx.x, acc[6]); acc[7] = fmaf(w3, xx.y, acc[7]);
    }
  }
  asm volatile("s_waitcnt lgkmcnt(0)" ::: "memory");
  if (G > 1){
    #pragma unroll
    for (int q = 0; q < 8; ++q){
      acc[q] += __shfl_xor(acc[q], 16);
      acc[q] += __shfl_xor(acc[q], 32);
    }
  }
  if (grp == 0){
    u32* ar = agg + (size_t)n * (2 * IN);
    ar[0 * NW + wi] = pack2bf(acc[0] * i0, acc[1] * i0);
    ar[1 * NW + wi] = pack2bf(acc[2] * i1, acc[3] * i1);
    ar[2 * NW + wi] = pack2bf(acc[4] * i2, acc[5] * i2);
    ar[3 * NW + wi] = pack2bf(acc[6] * i3, acc[7] * i3);
  }
}

// ---------------- stacked-head GEMM + bias + LN + ReLU + next-layer logits ----------------
// C[n][c] = sum_f agg[n][f] * Wstk[c][f]  (Wstk pre-scaled by 1/4)
template<int KF, int NEXT>   // KF = 128 or 512
__global__ __launch_bounds__(256) void k_gemmLN(const u16* __restrict__ Ab,   // agg [N,KF] bf16
                                                const u16* __restrict__ Bt,   // [128][KF] bf16
                                                const float* __restrict__ bias,
                                                const float* __restrict__ lng,
                                                const float* __restrict__ lnb,
                                                const float* __restrict__ vfN, // next vfold (1024 f) or junk
                                                u16* __restrict__ Xout,       // [N,128] bf16
                                                float4* __restrict__ s_srcN,
                                                float4* __restrict__ s_dstN,
                                                int M){
  const int CH = 136;   // BK=128 + 8 pad
  __shared__ u16 ldsA[64 * CH];
  __shared__ u16 ldsB[128 * CH];
  __shared__ float prm[384 + 1024];
  int bm = blockIdx.x * 64;
  int t = threadIdx.x;
  for (int i = t; i < 384; i += 256){
    const float* sp = (i < 128) ? bias : ((i < 256) ? lng : lnb);
    prm[i] = sp[i & 127];
  }
  if (NEXT){
    for (int i = t; i < 1024; i += 256) prm[384 + i] = vfN[i];
  }
  int w = t >> 6, lane = t & 63, r = lane & 15, g = lane >> 4;
  f32x4 acc[8];
  #pragma unroll
  for (int i = 0; i < 8; ++i) acc[i] = (f32x4){0.f, 0.f, 0.f, 0.f};

  for (int kt = 0; kt < KF; kt += 128){
    for (int f = t; f < 64 * 16; f += 256){
      int row = f >> 4, c8 = f & 15;
      int gm = bm + row;
      uint4 vv = make_uint4(0, 0, 0, 0);
      if (gm < M) vv = *(const uint4*)(Ab + (size_t)gm * KF + kt + c8 * 8);
      *(uint4*)&ldsA[row * CH + c8 * 8] = vv;
    }
    for (int f = t; f < 128 * 16; f += 256){
      int row = f >> 4, c8 = f & 15;
      *(uint4*)&ldsB[row * CH + c8 * 8] = *(const uint4*)(Bt + (size_t)row * KF + kt + c8 * 8);
    }
    __syncthreads();
    #pragma unroll
    for (int k0 = 0; k0 < 128; k0 += 32){
      s16x8 a = *(const s16x8*)(&ldsA[(w * 16 + r) * CH + k0 + g * 8]);
      #pragma unroll
      for (int nf = 0; nf < 8; ++nf){
        s16x8 b = *(const s16x8*)(&ldsB[(nf * 16 + r) * CH + k0 + g * 8]);
        acc[nf] = __builtin_amdgcn_mfma_f32_16x16x32_bf16(a, b, acc[nf], 0, 0, 0);
      }
    }
    __syncthreads();
  }

  // epilogue: row gm = bm + w*16 + g*4 + i; channel = nf*16 + r (16 r-lanes per row)
  #pragma unroll
  for (int i = 0; i < 4; ++i){
    int gm = bm + w * 16 + g * 4 + i;
    float tt[8];
    float rs = 0.f;
    #pragma unroll
    for (int nf = 0; nf < 8; ++nf){
      tt[nf] = acc[nf][i] + prm[nf * 16 + r];
      rs += tt[nf];
    }
    rs += __shfl_xor(rs, 1); rs += __shfl_xor(rs, 2);
    rs += __shfl_xor(rs, 4); rs += __shfl_xor(rs, 8);
    float mu = rs * (1.f / 128.f);
    float sq = 0.f;
    #pragma unroll
    for (int nf = 0; nf < 8; ++nf){ tt[nf] -= mu; sq += tt[nf] * tt[nf]; }
    sq += __shfl_xor(sq, 1); sq += __shfl_xor(sq, 2);
    sq += __shfl_xor(sq, 4); sq += __shfl_xor(sq, 8);
    float invs = rsqrtf(sq * (1.f / 128.f) + LN_EPS);
    float pa0 = 0.f, pa1 = 0.f, pa2 = 0.f, pa3 = 0.f;
    float pd0 = 0.f, pd1 = 0.f, pd2 = 0.f, pd3 = 0.f;
    #pragma unroll
    for (int nf = 0; nf < 8; ++nf){
      int ch = nf * 16 + r;
      float o = fmaxf(tt[nf] * invs * prm[128 + ch] + prm[256 + ch], 0.f);
      if (gm < M) Xout[(size_t)gm * HIDD + ch] = f2bf(o);
      if (NEXT){
        pa0 = fmaf(o, prm[384 + ch * 4 + 0], pa0);
        pa1 = fmaf(o, prm[384 + ch * 4 + 1], pa1);
        pa2 = fmaf(o, prm[384 + ch * 4 + 2], pa2);
        pa3 = fmaf(o, prm[384 + ch * 4 + 3], pa3);
        pd0 = fmaf(o, prm[384 + 512 + ch * 4 + 0], pd0);
        pd1 = fmaf(o, prm[384 + 512 + ch * 4 + 1], pd1);
        pd2 = fmaf(o, prm[384 + 512 + ch * 4 + 2], pd2);
        pd3 = fmaf(o, prm[384 + 512 + ch * 4 + 3], pd3);
      }
    }
    if (NEXT){
      #pragma unroll
      for (int m = 1; m < 16; m <<= 1){
        pa0 += __shfl_xor(pa0, m); pa1 += __shfl_xor(pa1, m);
        pa2 += __shfl_xor(pa2, m); pa3 += __shfl_xor(pa3, m);
        pd0 += __shfl_xor(pd0, m); pd1 += __shfl_xor(pd1, m);
        pd2 += __shfl_xor(pd2, m); pd3 += __shfl_xor(pd3, m);
      }
      if (r == 0 && gm < M){
        s_srcN[gm] = make_float4(pa0, pa1, pa2, pa3);
        s_dstN[gm] = make_float4(pd0, pd1, pd2, pd3);
      }
    }
  }
}

// ---------------- global mean pool: vectorized cooperative reads ----------------
__global__ __launch_bounds__(256) void k_pool(const u32* __restrict__ Xw,   // bf16 words [N,64]
                                              const int* __restrict__ bnd,
                                              float* __restrict__ out){
  __shared__ float red[16][128];
  int g = blockIdx.x;
  int s = bnd[g], e = bnd[g + 1];
  int rg = threadIdx.x >> 4;      // 0..15 row group
  int cg = threadIdx.x & 15;      // 0..15 channel group (8 channels each)
  float acc[8] = {0,0,0,0,0,0,0,0};
  for (int n = s + rg; n < e; n += 16){
    uint4 v = *(const uint4*)(Xw + (size_t)n * 64 + cg * 4);
    float2 p0 = bf2f(v.x), p1 = bf2f(v.y), p2 = bf2f(v.z), p3 = bf2f(v.w);
    acc[0] += p0.x; acc[1] += p0.y; acc[2] += p1.x; acc[3] += p1.y;
    acc[4] += p2.x; acc[5] += p2.y; acc[6] += p3.x; acc[7] += p3.y;
  }
  #pragma unroll
  for (int i = 0; i < 8; ++i) red[rg][cg * 8 + i] = acc[i];
  __syncthreads();
  int c = threadIdx.x;
  if (c < 128){
    float sthis = 0.f;
    #pragma unroll
    for (int r = 0; r < 16; ++r) sthis += red[r][c];
    out[g * HIDD + c] = sthis / fmaxf((float)(e - s), 1.f);
  }
}

extern "C" void kernel_launch(void* const* d_in, const int* in_sizes, int n_in,
                              void* d_out, int out_size, void* d_ws, size_t ws_size,
                              hipStream_t stream){
  const float* x        = (const float*)d_in[0];
  const float* ea       = (const float*)d_in[1];
  const float* lin_w[3] = {(const float*)d_in[2], (const float*)d_in[3], (const float*)d_in[4]};
  const float* lin_edge = (const float*)d_in[5];
  const float* att_src  = (const float*)d_in[6];
  const float* att_dst  = (const float*)d_in[7];
  const float* att_edge = (const float*)d_in[8];
  const float* bias     = (const float*)d_in[9];
  const float* lng      = (const float*)d_in[10];
  const float* lnb      = (const float*)d_in[11];
  const int*   eidx     = (const int*)d_in[12];
  const int*   batch    = (const int*)d_in[13];
  const int*   srcp = eidx;
  const int*   dstp = eidx + N_EDG;

  char* ws = (char*)d_ws;
  size_t off = 0;
  auto alloc = [&](size_t bytes)->char*{
    size_t o = off;
    off = (off + bytes + 511) & ~(size_t)511;
    return ws + o;
  };
  int*   cursor   = (int*)  alloc((size_t)N_NODES * 4);
  int*   bnd      = (int*)  alloc((size_t)(NB + 1) * 4);
  float* s_src    = (float*)alloc((size_t)N_NODES * 4 * 4);
  float* s_dst    = (float*)alloc((size_t)N_NODES * 4 * 4);
  float* vfold    = (float*)alloc((size_t)3 * 1152 * 4);
  u32*   erec     = (u32*)  alloc((size_t)N_NODES * PAD * 32);
  u32*   agg      = (u32*)  alloc((size_t)N_NODES * 256 * 4);   // up to [N,512] bf16
  u16*   xbf0     = (u16*)  alloc((size_t)N_NODES * EMBD * 2);
  u16*   xbfA     = (u16*)  alloc((size_t)N_NODES * HIDD * 2);
  u16*   xbfB     = (u16*)  alloc((size_t)N_NODES * HIDD * 2);
  u16*   wstk0    = (u16*)  alloc((size_t)128 * 128 * 2);
  u16*   wstk1    = (u16*)  alloc((size_t)128 * 512 * 2);
  u16*   wstk2    = (u16*)  alloc((size_t)128 * 512 * 2);

  k_setup<<<3249, 256, 0, stream>>>(lin_w[0], lin_w[1], lin_w[2], lin_edge,
                                    att_src, att_dst, att_edge, x, batch,
                                    vfold, wstk0, wstk1, wstk2, xbf0, bnd, cursor);
  k_edgescatter<<<1329, 256, 0, stream>>>(ea, srcp, dstp, cursor, vfold, erec,
                                          x, (float4*)s_src, (float4*)s_dst);

  int aggrGrid = (N_NODES + 3) / 4;
  int gemmGrid = (N_NODES + 63) / 64;

  // ---- layer 0 ----
  k_aggr<EMBD><<<aggrGrid, 256, 0, stream>>>((const u32*)xbf0, erec,
      (const float4*)s_src, (const float4*)s_dst, cursor, 0, agg);
  k_gemmLN<128, 1><<<gemmGrid, 256, 0, stream>>>((const u16*)agg, wstk0,
      bias + 0 * HIDD, lng + 0 * HIDD, lnb + 0 * HIDD, vfold + 1 * 1152,
      xbfA, (float4*)s_src, (float4*)s_dst, N_NODES);

  // ---- layer 1 ----
  k_aggr<HIDD><<<aggrGrid, 256, 0, stream>>>((const u32*)xbfA, erec,
      (const float4*)s_src, (const float4*)s_dst, cursor, 1, agg);
  k_gemmLN<512, 1><<<gemmGrid, 256, 0, stream>>>((const u16*)agg, wstk1,
      bias + 1 * HIDD, lng + 1 * HIDD, lnb + 1 * HIDD, vfold + 2 * 1152,
      xbfB, (float4*)s_src, (float4*)s_dst, N_NODES);

  // ---- layer 2 ----
  k_aggr<HIDD><<<aggrGrid, 256, 0, stream>>>((const u32*)xbfB, erec,
      (const float4*)s_src, (const float4*)s_dst, cursor, 2, agg);
  k_gemmLN<512, 0><<<gemmGrid, 256, 0, stream>>>((const u16*)agg, wstk2,
      bias + 2 * HIDD, lng + 2 * HIDD, lnb + 2 * HIDD, vfold,
      xbfA, (float4*)s_src, (float4*)s_dst, N_NODES);

  k_pool<<<NB, 256, 0, stream>>>((const u32*)xbfA, bnd, (float*)d_out);
}